// Round 3
// baseline (2435.613 us; speedup 1.0000x reference)
//
#include <hip/hip_runtime.h>
#include <cfloat>
#include <cmath>

#define B_ 1024
#define D_ 256
#define H_ 512
#define N_ 100000
#define K_ 96
#define C_ 10
#define SAMP 8192      // sample columns for threshold estimation
#define CAPC 4096      // per-row candidate capacity (expected ~1170 survivors)

typedef __attribute__((ext_vector_type(8))) short bf16x8;
typedef __attribute__((ext_vector_type(4))) float f32x4;

__device__ __forceinline__ float bf2f(ushort h) {
    union { unsigned u; float f; } v; v.u = ((unsigned)h) << 16; return v.f;
}
__device__ __forceinline__ ushort f2bf(float f) {
    union { float f; unsigned u; } v; v.f = f;
    unsigned u = v.u;
    unsigned r = (u + 0x7fffu + ((u >> 16) & 1u)) >> 16;
    return (ushort)r;
}
// monotone fp32 -> u32 (ascending), and inverse
__device__ __forceinline__ unsigned f2key(float f) {
    unsigned u = __float_as_uint(f);
    return (u & 0x80000000u) ? ~u : (u | 0x80000000u);
}

#define GLDS(g, l)                                                            \
    __builtin_amdgcn_global_load_lds(                                         \
        (const __attribute__((address_space(1))) void*)(g),                   \
        (__attribute__((address_space(3))) void*)(l), 16, 0, 0)

// ---------------------------------------------------------------------------
// fp32 tiled GEMM (kept for tiny fp32 GEMMs: Wc, xe, xk)
// ---------------------------------------------------------------------------
template <int RELU>
__global__ __launch_bounds__(256) void gemm_nn(const float* __restrict__ A,
                                               const float* __restrict__ Bm,
                                               const float* __restrict__ bias,
                                               float* __restrict__ Cm,
                                               int M, int N, int Kd) {
    __shared__ float sA[16][68];
    __shared__ float sB[16][64];
    const int t  = threadIdx.x;
    const int tx = t & 15, ty = t >> 4;
    const int m0 = blockIdx.y * 64;
    const int n0 = blockIdx.x * 64;
    const int lr = t >> 2;
    const int lk = (t & 3) << 2;
    const int bk = t >> 4;
    const int bn = (t & 15) << 2;

    float acc[4][4] = {};
    for (int k0 = 0; k0 < Kd; k0 += 16) {
        float4 av = make_float4(0.f, 0.f, 0.f, 0.f);
        if (m0 + lr < M)
            av = *(const float4*)(A + (size_t)(m0 + lr) * Kd + k0 + lk);
        sA[lk + 0][lr] = av.x; sA[lk + 1][lr] = av.y;
        sA[lk + 2][lr] = av.z; sA[lk + 3][lr] = av.w;
        float4 bv = *(const float4*)(Bm + (size_t)(k0 + bk) * N + n0 + bn);
        *(float4*)&sB[bk][bn] = bv;
        __syncthreads();
#pragma unroll
        for (int kk = 0; kk < 16; ++kk) {
            float4 a4 = *(const float4*)&sA[kk][ty << 2];
            float4 b4 = *(const float4*)&sB[kk][tx << 2];
            float ar[4] = {a4.x, a4.y, a4.z, a4.w};
            float br[4] = {b4.x, b4.y, b4.z, b4.w};
#pragma unroll
            for (int i = 0; i < 4; ++i)
#pragma unroll
                for (int j = 0; j < 4; ++j)
                    acc[i][j] = fmaf(ar[i], br[j], acc[i][j]);
        }
        __syncthreads();
    }
#pragma unroll
    for (int i = 0; i < 4; ++i) {
        int row = m0 + (ty << 2) + i;
        if (row < M) {
            int col = n0 + (tx << 2);
            float b0 = 0.f, b1 = 0.f, b2 = 0.f, b3 = 0.f;
            if (bias) { b0 = bias[col]; b1 = bias[col + 1]; b2 = bias[col + 2]; b3 = bias[col + 3]; }
            float4 o;
            o.x = acc[i][0] + b0; o.y = acc[i][1] + b1;
            o.z = acc[i][2] + b2; o.w = acc[i][3] + b3;
            if (RELU) {
                o.x = fmaxf(o.x, 0.f); o.y = fmaxf(o.y, 0.f);
                o.z = fmaxf(o.z, 0.f); o.w = fmaxf(o.w, 0.f);
            }
            *(float4*)(Cm + (size_t)row * N + col) = o;
        }
    }
}

// ---------------------------------------------------------------------------
// bf16 MFMA NT GEMM: C = epilogue(A[M,K] @ B[N,K]^T)
// 128x128 tile, BK=32, 4 waves, each 4x4 tiles of 16x16x32 MFMA.
// MODE 0: out bf16               MODE 1: +bias, relu, out bf16
// MODE 2: sim -sqrt(max(q2+c2-2acc,0)) -> fp32 Cout
// MODE 3: +bias (no relu), out bf16
// MODE 4: sim value, filter >= thr[row], append (val,idx) to cand buffers
// ---------------------------------------------------------------------------
template <int MODE>
__global__ __launch_bounds__(256) void gemm_nt(const ushort* __restrict__ A,
                                               const ushort* __restrict__ Bv,
                                               const float* __restrict__ bias,
                                               const float* __restrict__ q2v,
                                               const float* __restrict__ c2v,
                                               const float* __restrict__ thrv,
                                               float* __restrict__ candV,
                                               int* __restrict__ candI,
                                               int* __restrict__ cnt,
                                               void* __restrict__ Cout,
                                               int M, int Nlim, int K,
                                               int ldc, int nvalid) {
    __shared__ ushort sA[128 * 32];
    __shared__ ushort sB[128 * 32];
    const int t = threadIdx.x;
    const int lane = t & 63, w = t >> 6;
    const int wm = w & 1, wn = w >> 1;
    const int m0 = blockIdx.y * 128, n0 = blockIdx.x * 128;

    f32x4 acc[4][4];
#pragma unroll
    for (int i = 0; i < 4; ++i)
#pragma unroll
        for (int j = 0; j < 4; ++j)
            acc[i][j] = (f32x4){0.f, 0.f, 0.f, 0.f};

    const int la = lane & 15, lk = lane >> 4;
    const int aoff = (wm * 64 + la) * 64 + lk * 16;
    const int boff = (wn * 64 + la) * 64 + lk * 16;
    const int r_ = t >> 2, cc_ = (t & 3);

    for (int k0 = 0; k0 < K; k0 += 32) {
#pragma unroll
        for (int q = 0; q < 2; ++q) {
            int r = r_ + q * 64;
            int ar = m0 + r; ar = (ar < M) ? ar : (M - 1);
            GLDS(A + (size_t)ar * K + k0 + cc_ * 8, (char*)sA + (q * 256 + t) * 16);
            int br = n0 + r; br = (br < Nlim) ? br : (Nlim - 1);
            GLDS(Bv + (size_t)br * K + k0 + cc_ * 8, (char*)sB + (q * 256 + t) * 16);
        }
        __syncthreads();
        bf16x8 af[4], bfr[4];
#pragma unroll
        for (int i = 0; i < 4; ++i)
            af[i] = *(const bf16x8*)((const char*)sA + aoff + i * 1024);
#pragma unroll
        for (int j = 0; j < 4; ++j)
            bfr[j] = *(const bf16x8*)((const char*)sB + boff + j * 1024);
#pragma unroll
        for (int i = 0; i < 4; ++i)
#pragma unroll
            for (int j = 0; j < 4; ++j)
                acc[i][j] = __builtin_amdgcn_mfma_f32_16x16x32_bf16(
                    af[i], bfr[j], acc[i][j], 0, 0, 0);
        __syncthreads();
    }

    const int rl = (lane >> 4) * 4, cl = lane & 15;
#pragma unroll
    for (int i = 0; i < 4; ++i) {
#pragma unroll
        for (int j = 0; j < 4; ++j) {
            int gc = n0 + wn * 64 + j * 16 + cl;
#pragma unroll
            for (int v = 0; v < 4; ++v) {
                int gr = m0 + wm * 64 + i * 16 + rl + v;
                if (gr < M && gc < nvalid) {
                    float val = acc[i][j][v];
                    if (MODE == 2 || MODE == 4) {
                        float d2 = q2v[gr] + c2v[gc] - 2.f * val;
                        float s = -sqrtf(fmaxf(d2, 0.f));
                        if (MODE == 2) {
                            ((float*)Cout)[(size_t)gr * ldc + gc] = s;
                        } else {
                            if (s >= thrv[gr]) {
                                int p = atomicAdd(&cnt[gr], 1);
                                if (p < CAPC) {
                                    candV[(size_t)gr * CAPC + p] = s;
                                    candI[(size_t)gr * CAPC + p] = gc;
                                }
                            }
                        }
                    } else {
                        if (MODE == 1 || MODE == 3) val += bias[gc];
                        if (MODE == 1) val = fmaxf(val, 0.f);
                        ((ushort*)Cout)[(size_t)gr * ldc + gc] = f2bf(val);
                    }
                }
            }
        }
    }
}

// ---------------------------------------------------------------------------
// per-row radix-select of the 96th-largest over the sample sim matrix
// ---------------------------------------------------------------------------
__global__ __launch_bounds__(256) void thr_select(const float* __restrict__ S,
                                                  float* __restrict__ thrArr) {
    __shared__ unsigned keys[SAMP];
    __shared__ int hist[256];
    __shared__ int sel[2];
    const int b = blockIdx.x, t = threadIdx.x;
    for (int i = t; i < SAMP; i += 256)
        keys[i] = f2key(S[(size_t)b * SAMP + i]);
    __syncthreads();
    unsigned prefix = 0, mask = 0;
    int rank = K_;
    for (int shift = 24; shift >= 0; shift -= 8) {
        hist[t & 255] = 0;
        __syncthreads();
        for (int i = t; i < SAMP; i += 256) {
            unsigned k = keys[i];
            if ((k & mask) == prefix) atomicAdd(&hist[(k >> shift) & 255], 1);
        }
        __syncthreads();
        if (t == 0) {
            int r = rank, d = 255;
            for (; d > 0; --d) { int c = hist[d]; if (r - c <= 0) break; r -= c; }
            sel[0] = d; sel[1] = (r < 1) ? 1 : r;
        }
        __syncthreads();
        prefix |= ((unsigned)sel[0]) << shift;
        rank = sel[1];
        mask |= (0xFFu << shift);
        __syncthreads();
    }
    if (t == 0) {
        unsigned u = prefix;
        unsigned f = (u & 0x80000000u) ? (u & 0x7FFFFFFFu) : ~u;
        thrArr[b] = __uint_as_float(f);
    }
}

// ---------------------------------------------------------------------------
// per-row exact top-96 from candidate buffer via radix select + compaction
// ---------------------------------------------------------------------------
__global__ __launch_bounds__(256) void final_select(const float* __restrict__ candV,
                                                    const int* __restrict__ candI,
                                                    const int* __restrict__ cnt,
                                                    float* __restrict__ topV,
                                                    int* __restrict__ topI) {
    __shared__ unsigned keys[CAPC];
    __shared__ int hist[256];
    __shared__ int sel[2];
    __shared__ int poscnt, eqcnt;
    const int b = blockIdx.x, t = threadIdx.x;
    int n = cnt[b]; if (n > CAPC) n = CAPC;
    for (int i = t; i < n; i += 256)
        keys[i] = f2key(candV[(size_t)b * CAPC + i]);
    __syncthreads();
    unsigned prefix = 0, mask = 0;
    int rank = K_;
    for (int shift = 24; shift >= 0; shift -= 8) {
        hist[t & 255] = 0;
        __syncthreads();
        for (int i = t; i < n; i += 256) {
            unsigned k = keys[i];
            if ((k & mask) == prefix) atomicAdd(&hist[(k >> shift) & 255], 1);
        }
        __syncthreads();
        if (t == 0) {
            int r = rank, d = 255;
            for (; d > 0; --d) { int c = hist[d]; if (r - c <= 0) break; r -= c; }
            sel[0] = d; sel[1] = (r < 1) ? 1 : r;
        }
        __syncthreads();
        prefix |= ((unsigned)sel[0]) << shift;
        rank = sel[1];
        mask |= (0xFFu << shift);
        __syncthreads();
    }
    unsigned kth = prefix;
    if (t == 0) { poscnt = 0; eqcnt = 0; }
    __syncthreads();
    for (int i = t; i < n; i += 256) {
        if (keys[i] > kth) {
            int p = atomicAdd(&poscnt, 1);
            topV[b * K_ + p] = candV[(size_t)b * CAPC + i];
            topI[b * K_ + p] = candI[(size_t)b * CAPC + i];
        }
    }
    __syncthreads();
    int base = poscnt;
    for (int i = t; i < n; i += 256) {
        if (keys[i] == kth) {
            int p = atomicAdd(&eqcnt, 1);
            if (base + p < K_) {
                topV[b * K_ + base + p] = candV[(size_t)b * CAPC + i];
                topI[b * K_ + base + p] = candI[(size_t)b * CAPC + i];
            }
        }
    }
}

__global__ void init_cnt(int* cnt) {
    int i = blockIdx.x * 256 + threadIdx.x;
    if (i < B_) cnt[i] = 0;
}

// ---------------------------------------------------------------------------
__global__ void conv_f2b(const float* __restrict__ in, ushort* __restrict__ out, int n) {
    int i = (blockIdx.x * 256 + threadIdx.x) * 4;
    int stride = gridDim.x * 256 * 4;
    for (; i < n; i += stride) {
        float4 v = *(const float4*)(in + i);
        ushort4 o;
        o.x = f2bf(v.x); o.y = f2bf(v.y); o.z = f2bf(v.z); o.w = f2bf(v.w);
        *(ushort4*)(out + i) = o;
    }
}

__global__ __launch_bounds__(256) void transpose_f2b(const float* __restrict__ in,
                                                     ushort* __restrict__ out,
                                                     int R, int Cn) {
    __shared__ float tile[32][33];
    int bx = blockIdx.x * 32, by = blockIdx.y * 32;
    int tx = threadIdx.x & 31, ty = threadIdx.x >> 5;
    int x = bx + tx;
#pragma unroll
    for (int dy = 0; dy < 32; dy += 8) {
        int y = by + ty + dy;
        if (x < Cn && y < R) tile[ty + dy][tx] = in[(size_t)y * Cn + x];
    }
    __syncthreads();
    int ox = by + tx;
#pragma unroll
    for (int dy = 0; dy < 32; dy += 8) {
        int oy = bx + ty + dy;
        if (ox < R && oy < Cn) out[(size_t)oy * R + ox] = f2bf(tile[tx][ty + dy]);
    }
}

__global__ __launch_bounds__(64) void rowsq_b(const ushort* __restrict__ X,
                                              float* __restrict__ outv) {
    const int r = blockIdx.x, t = threadIdx.x;
    const ushort* p = X + (size_t)r * H_;
    ushort4 a = *(const ushort4*)(p + t * 4);
    ushort4 b = *(const ushort4*)(p + 256 + t * 4);
    float ax = bf2f(a.x), ay = bf2f(a.y), az = bf2f(a.z), aw = bf2f(a.w);
    float bx = bf2f(b.x), by = bf2f(b.y), bz = bf2f(b.z), bw = bf2f(b.w);
    float v = ax * ax + ay * ay + az * az + aw * aw +
              bx * bx + by * by + bz * bz + bw * bw;
    for (int off = 32; off > 0; off >>= 1) v += __shfl_down(v, off);
    if (t == 0) outv[r] = v;
}

__global__ void bcomb_k(const float* __restrict__ b_enc,
                        const float* __restrict__ W_key,
                        const float* __restrict__ b_key,
                        float* __restrict__ b_comb) {
    int h = blockIdx.x * 256 + threadIdx.x;
    if (h >= H_) return;
    float acc = b_key[h];
    for (int m = 0; m < H_; ++m)
        acc = fmaf(b_enc[m], W_key[(size_t)m * H_ + h], acc);
    b_comb[h] = acc;
}

__global__ __launch_bounds__(128) void softmax_k(const float* __restrict__ topVal,
                                                 float* __restrict__ attn) {
    __shared__ float red[128];
    const int b = blockIdx.x, t = threadIdx.x;
    float v = (t < K_) ? topVal[b * K_ + t] : -FLT_MAX;
    red[t] = v; __syncthreads();
    for (int s = 64; s > 0; s >>= 1) {
        if (t < s) red[t] = fmaxf(red[t], red[t + s]);
        __syncthreads();
    }
    float m = red[0]; __syncthreads();
    float e = (t < K_) ? expf(v - m) : 0.f;
    red[t] = e; __syncthreads();
    for (int s = 64; s > 0; s >>= 1) {
        if (t < s) red[t] += red[t + s];
        __syncthreads();
    }
    float ssum = red[0];
    if (t < K_) attn[b * K_ + t] = e / ssum;
}

__global__ __launch_bounds__(128) void gather_diff_b(const float* __restrict__ XK,
                                                     const ushort* __restrict__ CK,
                                                     const int* __restrict__ topI,
                                                     ushort* __restrict__ diff,
                                                     int b0) {
    const int r = blockIdx.x;
    const int b = b0 + r / K_;
    const int idx = topI[b * K_ + (r % K_)];
    const int t = threadIdx.x;
    float4 xv = *(const float4*)(XK + (size_t)b * H_ + t * 4);
    ushort4 cv = *(const ushort4*)(CK + (size_t)idx * H_ + t * 4);
    ushort4 o;
    o.x = f2bf(xv.x - bf2f(cv.x));
    o.y = f2bf(xv.y - bf2f(cv.y));
    o.z = f2bf(xv.z - bf2f(cv.z));
    o.w = f2bf(xv.w - bf2f(cv.w));
    *(ushort4*)(diff + (size_t)r * H_ + t * 4) = o;
}

__global__ __launch_bounds__(256) void reduce_ctx(const float* __restrict__ attn,
                                                  const int* __restrict__ topI,
                                                  const int* __restrict__ labels,
                                                  const float* __restrict__ E,
                                                  const ushort* __restrict__ tout,
                                                  const float* __restrict__ xe,
                                                  float* __restrict__ out, int b0) {
    const int bl = blockIdx.x;
    const int b = b0 + bl;
    const int t = threadIdx.x;
    float a0 = 0.f, a1 = 0.f;
    for (int k = 0; k < K_; ++k) {
        float w = attn[b * K_ + k];
        int idx = topI[b * K_ + k];
        int lab = labels[idx];
        const float* el = E + (size_t)lab * H_;
        const ushort* tr = tout + (size_t)(bl * K_ + k) * H_;
        a0 = fmaf(w, el[t] + bf2f(tr[t]), a0);
        a1 = fmaf(w, el[t + 256] + bf2f(tr[t + 256]), a1);
    }
    out[(size_t)b * H_ + t]       = xe[(size_t)b * H_ + t] + a0;
    out[(size_t)b * H_ + t + 256] = xe[(size_t)b * H_ + t + 256] + a1;
}

// ---------------------------------------------------------------------------
extern "C" void kernel_launch(void* const* d_in, const int* in_sizes, int n_in,
                              void* d_out, int out_size, void* d_ws, size_t ws_size,
                              hipStream_t stream) {
    const float* x      = (const float*)d_in[0];
    const float* cx     = (const float*)d_in[1];
    const int*   labels = (const int*)d_in[2];
    const float* W_enc  = (const float*)d_in[3];
    const float* b_enc  = (const float*)d_in[4];
    const float* W_key  = (const float*)d_in[5];
    const float* b_key  = (const float*)d_in[6];
    // d_in[7]=W_val, d_in[8]=b_val dead (gather unused in reference)
    const float* E_label = (const float*)d_in[9];
    const float* W_t1   = (const float*)d_in[10];
    const float* b_t1   = (const float*)d_in[11];
    const float* W_t2   = (const float*)d_in[12];
    float* out = (float*)d_out;

    char* base = (char*)d_ws;
    size_t off = 0;
    auto take = [&](size_t n) -> char* {
        char* p = base + off;
        off = (off + n + 255) & ~(size_t)255;
        return p;
    };
    float*  Wc    = (float*)take((size_t)D_ * H_ * 4);
    float*  bc    = (float*)take((size_t)H_ * 4);
    ushort* WcT   = (ushort*)take((size_t)H_ * D_ * 2);
    ushort* Wt1T  = (ushort*)take((size_t)H_ * H_ * 2);
    ushort* Wt2T  = (ushort*)take((size_t)H_ * H_ * 2);
    float*  xe    = (float*)take((size_t)B_ * H_ * 4);
    float*  xk    = (float*)take((size_t)B_ * H_ * 4);
    ushort* xkb   = (ushort*)take((size_t)B_ * H_ * 2);
    float*  q2    = (float*)take((size_t)B_ * 4);
    ushort* ckb   = (ushort*)take((size_t)N_ * H_ * 2);
    float*  c2    = (float*)take((size_t)N_ * 4);
    float*  topV  = (float*)take((size_t)B_ * K_ * 4);
    int*    topI  = (int*)take((size_t)B_ * K_ * 4);
    float*  thr   = (float*)take((size_t)B_ * 4);
    float*  attn  = (float*)take((size_t)B_ * K_ * 4);
    int*    cnt   = (int*)take((size_t)B_ * 4);
    float*  candV = (float*)take((size_t)B_ * CAPC * 4);
    int*    candI = (int*)take((size_t)B_ * CAPC * 4);
    char*   big   = base + off;      // shared region: cxb -> simSmall -> stage4
    size_t rem = (ws_size > off) ? (ws_size - off) : 0;

    ushort* cxb      = (ushort*)big;                 // N*D*2   = 51.2 MB
    float*  simSmall = (float*)big;                  // B*SAMP*4= 33.6 MB (after cxb dead)
    // stage-4 chunk size from remaining region
    long long bcq = (long long)(rem / ((size_t)K_ * H_ * 2 * 2));
    if (bcq > B_) bcq = B_;
    if (bcq < 1) bcq = 1;
    int Bc = (int)bcq;

    // stage 0: combined candidate weights + transposed bf16 weights
    {
        dim3 g(H_ / 64, D_ / 64);
        gemm_nn<0><<<g, 256, 0, stream>>>(W_enc, W_key, nullptr, Wc, D_, H_, H_);
        bcomb_k<<<(H_ + 255) / 256, 256, 0, stream>>>(b_enc, W_key, b_key, bc);
        dim3 gt1((H_ + 31) / 32, (D_ + 31) / 32);
        transpose_f2b<<<gt1, 256, 0, stream>>>(Wc, WcT, D_, H_);
        dim3 gt2((H_ + 31) / 32, (H_ + 31) / 32);
        transpose_f2b<<<gt2, 256, 0, stream>>>(W_t1, Wt1T, H_, H_);
        transpose_f2b<<<gt2, 256, 0, stream>>>(W_t2, Wt2T, H_, H_);
    }
    // stage 1: query encodes (fp32, tiny) + bf16 conversions
    {
        dim3 gx(H_ / 64, B_ / 64);
        gemm_nn<0><<<gx, 256, 0, stream>>>(x, W_enc, b_enc, xe, B_, H_, D_);
        gemm_nn<0><<<gx, 256, 0, stream>>>(x, Wc, bc, xk, B_, H_, D_);
        conv_f2b<<<1024, 256, 0, stream>>>(xk, xkb, B_ * H_);
        conv_f2b<<<2048, 256, 0, stream>>>(cx, cxb, N_ * D_);
    }
    // stage 2: candidate keys via bf16 MFMA (bias, no relu)
    {
        dim3 g(H_ / 128, (N_ + 127) / 128);
        gemm_nt<3><<<g, 256, 0, stream>>>(cxb, WcT, bc, nullptr, nullptr,
                                          nullptr, nullptr, nullptr, nullptr,
                                          ckb, N_, H_, D_, H_, H_);
    }
    rowsq_b<<<N_, 64, 0, stream>>>(ckb, c2);
    rowsq_b<<<B_, 64, 0, stream>>>(xkb, q2);

    // stage 3a: sample sim GEMM (first SAMP candidates) -> per-row threshold
    {
        dim3 g(SAMP / 128, B_ / 128);
        gemm_nt<2><<<g, 256, 0, stream>>>(xkb, ckb, nullptr, q2, c2,
                                          nullptr, nullptr, nullptr, nullptr,
                                          simSmall, B_, N_, H_, SAMP, SAMP);
        thr_select<<<B_, 256, 0, stream>>>(simSmall, thr);
    }
    // stage 3b: fused sim GEMM + threshold filter over all N (no sim matrix)
    init_cnt<<<(B_ + 255) / 256, 256, 0, stream>>>(cnt);
    {
        dim3 g((N_ + 127) / 128, B_ / 128);
        gemm_nt<4><<<g, 256, 0, stream>>>(xkb, ckb, nullptr, q2, c2,
                                          thr, candV, candI, cnt,
                                          nullptr, B_, N_, H_, 0, N_);
    }
    // stage 3c: exact per-row top-96 from candidates
    final_select<<<B_, 256, 0, stream>>>(candV, candI, cnt, topV, topI);
    softmax_k<<<B_, 128, 0, stream>>>(topV, attn);

    // stage 4: correction MLP (bf16 MFMA) + weighted reduce
    ushort* diffB = (ushort*)big;
    ushort* hB = (ushort*)(big + (size_t)Bc * K_ * H_ * 2);
    for (int b0 = 0; b0 < B_; b0 += Bc) {
        int bcn = min(Bc, B_ - b0);
        int Mrows = bcn * K_;
        gather_diff_b<<<Mrows, 128, 0, stream>>>(xk, ckb, topI, diffB, b0);
        dim3 g1(H_ / 128, (Mrows + 127) / 128);
        gemm_nt<1><<<g1, 256, 0, stream>>>(diffB, Wt1T, b_t1, nullptr, nullptr,
                                           nullptr, nullptr, nullptr, nullptr,
                                           hB, Mrows, H_, H_, H_, H_);
        gemm_nt<0><<<g1, 256, 0, stream>>>(hB, Wt2T, nullptr, nullptr, nullptr,
                                           nullptr, nullptr, nullptr, nullptr,
                                           diffB, Mrows, H_, H_, H_, H_);
        reduce_ctx<<<bcn, 256, 0, stream>>>(attn, topI, labels, E_label,
                                            diffB, xe, out, b0);
    }
}

// Round 4
// 1791.447 us; speedup vs baseline: 1.3596x; 1.3596x over previous
//
#include <hip/hip_runtime.h>
#include <cfloat>
#include <cmath>

#define B_ 1024
#define D_ 256
#define H_ 512
#define N_ 100000
#define K_ 96
#define C_ 10
#define SAMP 8192      // sample columns for threshold estimation
#define CAPC 4096      // per-row candidate capacity (expected ~1170 survivors)

typedef __attribute__((ext_vector_type(8))) short bf16x8;
typedef __attribute__((ext_vector_type(4))) float f32x4;

__device__ __forceinline__ float bf2f(ushort h) {
    union { unsigned u; float f; } v; v.u = ((unsigned)h) << 16; return v.f;
}
__device__ __forceinline__ ushort f2bf(float f) {
    union { float f; unsigned u; } v; v.f = f;
    unsigned u = v.u;
    unsigned r = (u + 0x7fffu + ((u >> 16) & 1u)) >> 16;
    return (ushort)r;
}
// monotone fp32 -> u32 (ascending)
__device__ __forceinline__ unsigned f2key(float f) {
    unsigned u = __float_as_uint(f);
    return (u & 0x80000000u) ? ~u : (u | 0x80000000u);
}

#define GLDS(g, l)                                                            \
    __builtin_amdgcn_global_load_lds(                                         \
        (const __attribute__((address_space(1))) void*)(g),                   \
        (__attribute__((address_space(3))) void*)(l), 16, 0, 0)

// ---------------------------------------------------------------------------
// fp32 tiled GEMM (kept for tiny fp32 GEMMs: Wc, xe, xk)
// ---------------------------------------------------------------------------
template <int RELU>
__global__ __launch_bounds__(256) void gemm_nn(const float* __restrict__ A,
                                               const float* __restrict__ Bm,
                                               const float* __restrict__ bias,
                                               float* __restrict__ Cm,
                                               int M, int N, int Kd) {
    __shared__ float sA[16][68];
    __shared__ float sB[16][64];
    const int t  = threadIdx.x;
    const int tx = t & 15, ty = t >> 4;
    const int m0 = blockIdx.y * 64;
    const int n0 = blockIdx.x * 64;
    const int lr = t >> 2;
    const int lk = (t & 3) << 2;
    const int bk = t >> 4;
    const int bn = (t & 15) << 2;

    float acc[4][4] = {};
    for (int k0 = 0; k0 < Kd; k0 += 16) {
        float4 av = make_float4(0.f, 0.f, 0.f, 0.f);
        if (m0 + lr < M)
            av = *(const float4*)(A + (size_t)(m0 + lr) * Kd + k0 + lk);
        sA[lk + 0][lr] = av.x; sA[lk + 1][lr] = av.y;
        sA[lk + 2][lr] = av.z; sA[lk + 3][lr] = av.w;
        float4 bv = *(const float4*)(Bm + (size_t)(k0 + bk) * N + n0 + bn);
        *(float4*)&sB[bk][bn] = bv;
        __syncthreads();
#pragma unroll
        for (int kk = 0; kk < 16; ++kk) {
            float4 a4 = *(const float4*)&sA[kk][ty << 2];
            float4 b4 = *(const float4*)&sB[kk][tx << 2];
            float ar[4] = {a4.x, a4.y, a4.z, a4.w};
            float br[4] = {b4.x, b4.y, b4.z, b4.w};
#pragma unroll
            for (int i = 0; i < 4; ++i)
#pragma unroll
                for (int j = 0; j < 4; ++j)
                    acc[i][j] = fmaf(ar[i], br[j], acc[i][j]);
        }
        __syncthreads();
    }
#pragma unroll
    for (int i = 0; i < 4; ++i) {
        int row = m0 + (ty << 2) + i;
        if (row < M) {
            int col = n0 + (tx << 2);
            float b0 = 0.f, b1 = 0.f, b2 = 0.f, b3 = 0.f;
            if (bias) { b0 = bias[col]; b1 = bias[col + 1]; b2 = bias[col + 2]; b3 = bias[col + 3]; }
            float4 o;
            o.x = acc[i][0] + b0; o.y = acc[i][1] + b1;
            o.z = acc[i][2] + b2; o.w = acc[i][3] + b3;
            if (RELU) {
                o.x = fmaxf(o.x, 0.f); o.y = fmaxf(o.y, 0.f);
                o.z = fmaxf(o.z, 0.f); o.w = fmaxf(o.w, 0.f);
            }
            *(float4*)(Cm + (size_t)row * N + col) = o;
        }
    }
}

// ---------------------------------------------------------------------------
// bf16 MFMA NT GEMM: C = epilogue(A[M,K] @ B[N,K]^T)
// 128x128 tile, BK=32, 4 waves, each 4x4 tiles of 16x16x32 MFMA.
// SWAP=1: blockIdx.x indexes M (consecutive blocks share the B-tile -> L2/L3
//         reuse of the big ckb operand).
// MODE 0: out bf16               MODE 1: +bias, relu, out bf16
// MODE 2: sim -sqrt(max(q2+c2-2acc,0)) -> fp32 Cout
// MODE 3: +bias (no relu), out bf16
// ---------------------------------------------------------------------------
template <int MODE, int SWAP>
__global__ __launch_bounds__(256) void gemm_nt(const ushort* __restrict__ A,
                                               const ushort* __restrict__ Bv,
                                               const float* __restrict__ bias,
                                               const float* __restrict__ q2v,
                                               const float* __restrict__ c2v,
                                               void* __restrict__ Cout,
                                               int M, int Nlim, int K,
                                               int ldc, int nvalid) {
    __shared__ ushort sA[128 * 32];
    __shared__ ushort sB[128 * 32];
    const int t = threadIdx.x;
    const int lane = t & 63, w = t >> 6;
    const int wm = w & 1, wn = w >> 1;
    const int m0 = (SWAP ? blockIdx.x : blockIdx.y) * 128;
    const int n0 = (SWAP ? blockIdx.y : blockIdx.x) * 128;

    f32x4 acc[4][4];
#pragma unroll
    for (int i = 0; i < 4; ++i)
#pragma unroll
        for (int j = 0; j < 4; ++j)
            acc[i][j] = (f32x4){0.f, 0.f, 0.f, 0.f};

    const int la = lane & 15, lk = lane >> 4;
    const int aoff = (wm * 64 + la) * 64 + lk * 16;
    const int boff = (wn * 64 + la) * 64 + lk * 16;
    const int r_ = t >> 2, cc_ = (t & 3);

    for (int k0 = 0; k0 < K; k0 += 32) {
#pragma unroll
        for (int q = 0; q < 2; ++q) {
            int r = r_ + q * 64;
            int ar = m0 + r; ar = (ar < M) ? ar : (M - 1);
            GLDS(A + (size_t)ar * K + k0 + cc_ * 8, (char*)sA + (q * 256 + t) * 16);
            int br = n0 + r; br = (br < Nlim) ? br : (Nlim - 1);
            GLDS(Bv + (size_t)br * K + k0 + cc_ * 8, (char*)sB + (q * 256 + t) * 16);
        }
        __syncthreads();
        bf16x8 af[4], bfr[4];
#pragma unroll
        for (int i = 0; i < 4; ++i)
            af[i] = *(const bf16x8*)((const char*)sA + aoff + i * 1024);
#pragma unroll
        for (int j = 0; j < 4; ++j)
            bfr[j] = *(const bf16x8*)((const char*)sB + boff + j * 1024);
#pragma unroll
        for (int i = 0; i < 4; ++i)
#pragma unroll
            for (int j = 0; j < 4; ++j)
                acc[i][j] = __builtin_amdgcn_mfma_f32_16x16x32_bf16(
                    af[i], bfr[j], acc[i][j], 0, 0, 0);
        __syncthreads();
    }

    const int rl = (lane >> 4) * 4, cl = lane & 15;
#pragma unroll
    for (int i = 0; i < 4; ++i) {
#pragma unroll
        for (int j = 0; j < 4; ++j) {
            int gc = n0 + wn * 64 + j * 16 + cl;
#pragma unroll
            for (int v = 0; v < 4; ++v) {
                int gr = m0 + wm * 64 + i * 16 + rl + v;
                if (gr < M && gc < nvalid) {
                    float val = acc[i][j][v];
                    if (MODE == 2) {
                        float d2 = q2v[gr] + c2v[gc] - 2.f * val;
                        ((float*)Cout)[(size_t)gr * ldc + gc] = -sqrtf(fmaxf(d2, 0.f));
                    } else {
                        if (MODE == 1 || MODE == 3) val += bias[gc];
                        if (MODE == 1) val = fmaxf(val, 0.f);
                        ((ushort*)Cout)[(size_t)gr * ldc + gc] = f2bf(val);
                    }
                }
            }
        }
    }
}

// ---------------------------------------------------------------------------
// per-row radix-select of the 96th-largest over the first SAMP columns
// ---------------------------------------------------------------------------
__global__ __launch_bounds__(256) void thr_select(const float* __restrict__ S,
                                                  int ld,
                                                  float* __restrict__ thrArr) {
    __shared__ unsigned keys[SAMP];
    __shared__ int hist[256];
    __shared__ int sel[2];
    const int b = blockIdx.x, t = threadIdx.x;
    for (int i = t; i < SAMP; i += 256)
        keys[i] = f2key(S[(size_t)b * ld + i]);
    __syncthreads();
    unsigned prefix = 0, mask = 0;
    int rank = K_;
    for (int shift = 24; shift >= 0; shift -= 8) {
        hist[t & 255] = 0;
        __syncthreads();
        for (int i = t; i < SAMP; i += 256) {
            unsigned k = keys[i];
            if ((k & mask) == prefix) atomicAdd(&hist[(k >> shift) & 255], 1);
        }
        __syncthreads();
        if (t == 0) {
            int r = rank, d = 255;
            for (; d > 0; --d) { int c = hist[d]; if (r - c <= 0) break; r -= c; }
            sel[0] = d; sel[1] = (r < 1) ? 1 : r;
        }
        __syncthreads();
        prefix |= ((unsigned)sel[0]) << shift;
        rank = sel[1];
        mask |= (0xFFu << shift);
        __syncthreads();
    }
    if (t == 0) {
        unsigned u = prefix;
        unsigned f = (u & 0x80000000u) ? (u & 0x7FFFFFFFu) : ~u;
        thrArr[b] = __uint_as_float(f);
    }
}

// ---------------------------------------------------------------------------
// streaming threshold filter over the materialized sim chunk.
// One block per (8192-col segment, row). Wave-aggregated global append.
// ---------------------------------------------------------------------------
__global__ __launch_bounds__(256) void filter_sim(const float* __restrict__ S,
                                                  int ld, int ncols, int j0,
                                                  const float* __restrict__ thrArr,
                                                  float* __restrict__ candV,
                                                  int* __restrict__ candI,
                                                  int* __restrict__ cnt) {
    const int b = blockIdx.y;
    const float thr = thrArr[b];
    const float* row = S + (size_t)b * ld;
    const int lane = threadIdx.x & 63;
    int c0 = blockIdx.x * 8192 + threadIdx.x * 4;
#pragma unroll
    for (int it = 0; it < 8; ++it, c0 += 1024) {
        if (c0 < ncols) {   // ncols % 4 == 0 always (100000 % 4 == 0)
            float4 vv4 = *(const float4*)(row + c0);
            float vv[4] = {vv4.x, vv4.y, vv4.z, vv4.w};
#pragma unroll
            for (int e = 0; e < 4; ++e) {
                bool take = vv[e] >= thr;
                unsigned long long m = __ballot(take);
                if (m) {
                    int lead = __ffsll((unsigned long long)m) - 1;
                    int nw = __popcll(m);
                    int basep = 0;
                    if (lane == lead) basep = atomicAdd(&cnt[b], nw);
                    basep = __shfl(basep, lead);
                    if (take) {
                        int pos = basep + __popcll(m & ((1ull << lane) - 1ull));
                        if (pos < CAPC) {
                            candV[(size_t)b * CAPC + pos] = vv[e];
                            candI[(size_t)b * CAPC + pos] = j0 + c0 + e;
                        }
                    }
                }
            }
        }
    }
}

// ---------------------------------------------------------------------------
// per-row exact top-96 from candidate buffer via radix select + compaction
// ---------------------------------------------------------------------------
__global__ __launch_bounds__(256) void final_select(const float* __restrict__ candV,
                                                    const int* __restrict__ candI,
                                                    const int* __restrict__ cnt,
                                                    float* __restrict__ topV,
                                                    int* __restrict__ topI) {
    __shared__ unsigned keys[CAPC];
    __shared__ int hist[256];
    __shared__ int sel[2];
    __shared__ int poscnt, eqcnt;
    const int b = blockIdx.x, t = threadIdx.x;
    int n = cnt[b]; if (n > CAPC) n = CAPC;
    for (int i = t; i < n; i += 256)
        keys[i] = f2key(candV[(size_t)b * CAPC + i]);
    __syncthreads();
    unsigned prefix = 0, mask = 0;
    int rank = K_;
    for (int shift = 24; shift >= 0; shift -= 8) {
        hist[t & 255] = 0;
        __syncthreads();
        for (int i = t; i < n; i += 256) {
            unsigned k = keys[i];
            if ((k & mask) == prefix) atomicAdd(&hist[(k >> shift) & 255], 1);
        }
        __syncthreads();
        if (t == 0) {
            int r = rank, d = 255;
            for (; d > 0; --d) { int c = hist[d]; if (r - c <= 0) break; r -= c; }
            sel[0] = d; sel[1] = (r < 1) ? 1 : r;
        }
        __syncthreads();
        prefix |= ((unsigned)sel[0]) << shift;
        rank = sel[1];
        mask |= (0xFFu << shift);
        __syncthreads();
    }
    unsigned kth = prefix;
    if (t == 0) { poscnt = 0; eqcnt = 0; }
    __syncthreads();
    for (int i = t; i < n; i += 256) {
        if (keys[i] > kth) {
            int p = atomicAdd(&poscnt, 1);
            topV[b * K_ + p] = candV[(size_t)b * CAPC + i];
            topI[b * K_ + p] = candI[(size_t)b * CAPC + i];
        }
    }
    __syncthreads();
    int base = poscnt;
    for (int i = t; i < n; i += 256) {
        if (keys[i] == kth) {
            int p = atomicAdd(&eqcnt, 1);
            if (base + p < K_) {
                topV[b * K_ + base + p] = candV[(size_t)b * CAPC + i];
                topI[b * K_ + base + p] = candI[(size_t)b * CAPC + i];
            }
        }
    }
}

__global__ void init_cnt(int* cnt) {
    int i = blockIdx.x * 256 + threadIdx.x;
    if (i < B_) cnt[i] = 0;
}

// ---------------------------------------------------------------------------
__global__ void conv_f2b(const float* __restrict__ in, ushort* __restrict__ out, int n) {
    int i = (blockIdx.x * 256 + threadIdx.x) * 4;
    int stride = gridDim.x * 256 * 4;
    for (; i < n; i += stride) {
        float4 v = *(const float4*)(in + i);
        ushort4 o;
        o.x = f2bf(v.x); o.y = f2bf(v.y); o.z = f2bf(v.z); o.w = f2bf(v.w);
        *(ushort4*)(out + i) = o;
    }
}

__global__ __launch_bounds__(256) void transpose_f2b(const float* __restrict__ in,
                                                     ushort* __restrict__ out,
                                                     int R, int Cn) {
    __shared__ float tile[32][33];
    int bx = blockIdx.x * 32, by = blockIdx.y * 32;
    int tx = threadIdx.x & 31, ty = threadIdx.x >> 5;
    int x = bx + tx;
#pragma unroll
    for (int dy = 0; dy < 32; dy += 8) {
        int y = by + ty + dy;
        if (x < Cn && y < R) tile[ty + dy][tx] = in[(size_t)y * Cn + x];
    }
    __syncthreads();
    int ox = by + tx;
#pragma unroll
    for (int dy = 0; dy < 32; dy += 8) {
        int oy = bx + ty + dy;
        if (ox < R && oy < Cn) out[(size_t)oy * R + ox] = f2bf(tile[tx][ty + dy]);
    }
}

__global__ __launch_bounds__(64) void rowsq_b(const ushort* __restrict__ X,
                                              float* __restrict__ outv) {
    const int r = blockIdx.x, t = threadIdx.x;
    const ushort* p = X + (size_t)r * H_;
    ushort4 a = *(const ushort4*)(p + t * 4);
    ushort4 b = *(const ushort4*)(p + 256 + t * 4);
    float ax = bf2f(a.x), ay = bf2f(a.y), az = bf2f(a.z), aw = bf2f(a.w);
    float bx = bf2f(b.x), by = bf2f(b.y), bz = bf2f(b.z), bw = bf2f(b.w);
    float v = ax * ax + ay * ay + az * az + aw * aw +
              bx * bx + by * by + bz * bz + bw * bw;
    for (int off = 32; off > 0; off >>= 1) v += __shfl_down(v, off);
    if (t == 0) outv[r] = v;
}

__global__ void bcomb_k(const float* __restrict__ b_enc,
                        const float* __restrict__ W_key,
                        const float* __restrict__ b_key,
                        float* __restrict__ b_comb) {
    int h = blockIdx.x * 256 + threadIdx.x;
    if (h >= H_) return;
    float acc = b_key[h];
    for (int m = 0; m < H_; ++m)
        acc = fmaf(b_enc[m], W_key[(size_t)m * H_ + h], acc);
    b_comb[h] = acc;
}

__global__ __launch_bounds__(128) void softmax_k(const float* __restrict__ topVal,
                                                 float* __restrict__ attn) {
    __shared__ float red[128];
    const int b = blockIdx.x, t = threadIdx.x;
    float v = (t < K_) ? topVal[b * K_ + t] : -FLT_MAX;
    red[t] = v; __syncthreads();
    for (int s = 64; s > 0; s >>= 1) {
        if (t < s) red[t] = fmaxf(red[t], red[t + s]);
        __syncthreads();
    }
    float m = red[0]; __syncthreads();
    float e = (t < K_) ? expf(v - m) : 0.f;
    red[t] = e; __syncthreads();
    for (int s = 64; s > 0; s >>= 1) {
        if (t < s) red[t] += red[t + s];
        __syncthreads();
    }
    float ssum = red[0];
    if (t < K_) attn[b * K_ + t] = e / ssum;
}

__global__ __launch_bounds__(128) void gather_diff_b(const float* __restrict__ XK,
                                                     const ushort* __restrict__ CK,
                                                     const int* __restrict__ topI,
                                                     ushort* __restrict__ diff,
                                                     int b0) {
    const int r = blockIdx.x;
    const int b = b0 + r / K_;
    const int idx = topI[b * K_ + (r % K_)];
    const int t = threadIdx.x;
    float4 xv = *(const float4*)(XK + (size_t)b * H_ + t * 4);
    ushort4 cv = *(const ushort4*)(CK + (size_t)idx * H_ + t * 4);
    ushort4 o;
    o.x = f2bf(xv.x - bf2f(cv.x));
    o.y = f2bf(xv.y - bf2f(cv.y));
    o.z = f2bf(xv.z - bf2f(cv.z));
    o.w = f2bf(xv.w - bf2f(cv.w));
    *(ushort4*)(diff + (size_t)r * H_ + t * 4) = o;
}

__global__ __launch_bounds__(256) void reduce_ctx(const float* __restrict__ attn,
                                                  const int* __restrict__ topI,
                                                  const int* __restrict__ labels,
                                                  const float* __restrict__ E,
                                                  const ushort* __restrict__ tout,
                                                  const float* __restrict__ xe,
                                                  float* __restrict__ out, int b0) {
    const int bl = blockIdx.x;
    const int b = b0 + bl;
    const int t = threadIdx.x;
    float a0 = 0.f, a1 = 0.f;
    for (int k = 0; k < K_; ++k) {
        float w = attn[b * K_ + k];
        int idx = topI[b * K_ + k];
        int lab = labels[idx];
        const float* el = E + (size_t)lab * H_;
        const ushort* tr = tout + (size_t)(bl * K_ + k) * H_;
        a0 = fmaf(w, el[t] + bf2f(tr[t]), a0);
        a1 = fmaf(w, el[t + 256] + bf2f(tr[t + 256]), a1);
    }
    out[(size_t)b * H_ + t]       = xe[(size_t)b * H_ + t] + a0;
    out[(size_t)b * H_ + t + 256] = xe[(size_t)b * H_ + t + 256] + a1;
}

// ---------------------------------------------------------------------------
extern "C" void kernel_launch(void* const* d_in, const int* in_sizes, int n_in,
                              void* d_out, int out_size, void* d_ws, size_t ws_size,
                              hipStream_t stream) {
    const float* x      = (const float*)d_in[0];
    const float* cx     = (const float*)d_in[1];
    const int*   labels = (const int*)d_in[2];
    const float* W_enc  = (const float*)d_in[3];
    const float* b_enc  = (const float*)d_in[4];
    const float* W_key  = (const float*)d_in[5];
    const float* b_key  = (const float*)d_in[6];
    // d_in[7]=W_val, d_in[8]=b_val dead (gather unused in reference)
    const float* E_label = (const float*)d_in[9];
    const float* W_t1   = (const float*)d_in[10];
    const float* b_t1   = (const float*)d_in[11];
    const float* W_t2   = (const float*)d_in[12];
    float* out = (float*)d_out;

    char* base = (char*)d_ws;
    size_t off = 0;
    auto take = [&](size_t n) -> char* {
        char* p = base + off;
        off = (off + n + 255) & ~(size_t)255;
        return p;
    };
    float*  Wc    = (float*)take((size_t)D_ * H_ * 4);
    float*  bc    = (float*)take((size_t)H_ * 4);
    ushort* WcT   = (ushort*)take((size_t)H_ * D_ * 2);
    ushort* Wt1T  = (ushort*)take((size_t)H_ * H_ * 2);
    ushort* Wt2T  = (ushort*)take((size_t)H_ * H_ * 2);
    float*  xe    = (float*)take((size_t)B_ * H_ * 4);
    float*  xk    = (float*)take((size_t)B_ * H_ * 4);
    ushort* xkb   = (ushort*)take((size_t)B_ * H_ * 2);
    float*  q2    = (float*)take((size_t)B_ * 4);
    ushort* ckb   = (ushort*)take((size_t)N_ * H_ * 2);
    float*  c2    = (float*)take((size_t)N_ * 4);
    float*  topV  = (float*)take((size_t)B_ * K_ * 4);
    int*    topI  = (int*)take((size_t)B_ * K_ * 4);
    float*  thr   = (float*)take((size_t)B_ * 4);
    float*  attn  = (float*)take((size_t)B_ * K_ * 4);
    int*    cnt   = (int*)take((size_t)B_ * 4);
    float*  candV = (float*)take((size_t)B_ * CAPC * 4);
    int*    candI = (int*)take((size_t)B_ * CAPC * 4);
    char*   big   = base + off;      // shared: cxb -> simBuf -> stage4 bufs
    size_t rem = (ws_size > off) ? (ws_size - off) : 0;

    ushort* cxb    = (ushort*)big;   // N*D*2 = 51.2 MB (dead after stage 2)
    float*  simBuf = (float*)big;    // B*Nc0*4

    long long nc = (long long)((rem / ((size_t)B_ * 4)) & ~(size_t)127);
    long long ncMax = ((N_ + 127) / 128) * 128;
    if (nc > ncMax) nc = ncMax;
    if (nc < SAMP) nc = SAMP;        // thr_select reads first SAMP cols of chunk 0
    int Nc0 = (int)nc;

    long long bcq = (long long)(rem / ((size_t)K_ * H_ * 2 * 2));
    if (bcq > B_) bcq = B_;
    if (bcq < 1) bcq = 1;
    int Bc = (int)bcq;

    // stage 0: combined candidate weights + transposed bf16 weights
    {
        dim3 g(H_ / 64, D_ / 64);
        gemm_nn<0><<<g, 256, 0, stream>>>(W_enc, W_key, nullptr, Wc, D_, H_, H_);
        bcomb_k<<<(H_ + 255) / 256, 256, 0, stream>>>(b_enc, W_key, b_key, bc);
        dim3 gt1((H_ + 31) / 32, (D_ + 31) / 32);
        transpose_f2b<<<gt1, 256, 0, stream>>>(Wc, WcT, D_, H_);
        dim3 gt2((H_ + 31) / 32, (H_ + 31) / 32);
        transpose_f2b<<<gt2, 256, 0, stream>>>(W_t1, Wt1T, H_, H_);
        transpose_f2b<<<gt2, 256, 0, stream>>>(W_t2, Wt2T, H_, H_);
    }
    // stage 1: query encodes (fp32, tiny) + bf16 conversions
    {
        dim3 gx(H_ / 64, B_ / 64);
        gemm_nn<0><<<gx, 256, 0, stream>>>(x, W_enc, b_enc, xe, B_, H_, D_);
        gemm_nn<0><<<gx, 256, 0, stream>>>(x, Wc, bc, xk, B_, H_, D_);
        conv_f2b<<<1024, 256, 0, stream>>>(xk, xkb, B_ * H_);
        conv_f2b<<<2048, 256, 0, stream>>>(cx, cxb, N_ * D_);
    }
    // stage 2: candidate keys via bf16 MFMA (bias, no relu)
    {
        dim3 g(H_ / 128, (N_ + 127) / 128);
        gemm_nt<3, 0><<<g, 256, 0, stream>>>(cxb, WcT, bc, nullptr, nullptr,
                                             ckb, N_, H_, D_, H_, H_);
    }
    rowsq_b<<<N_, 64, 0, stream>>>(ckb, c2);
    rowsq_b<<<B_, 64, 0, stream>>>(xkb, q2);

    // stage 3: chunked sim GEMM -> (chunk 0: threshold) -> streaming filter
    init_cnt<<<(B_ + 255) / 256, 256, 0, stream>>>(cnt);
    for (int j0 = 0; j0 < N_; j0 += Nc0) {
        int ncols = min(Nc0, N_ - j0);
        dim3 g(B_ / 128, (ncols + 127) / 128);   // SWAP=1: x=M so B-tile shared
        gemm_nt<2, 1><<<g, 256, 0, stream>>>(xkb, ckb + (size_t)j0 * H_, nullptr,
                                             q2, c2 + j0, simBuf,
                                             B_, N_ - j0, H_, Nc0, ncols);
        if (j0 == 0)
            thr_select<<<B_, 256, 0, stream>>>(simBuf, Nc0, thr);
        dim3 gf((ncols + 8191) / 8192, B_);
        filter_sim<<<gf, 256, 0, stream>>>(simBuf, Nc0, ncols, j0, thr,
                                           candV, candI, cnt);
    }
    final_select<<<B_, 256, 0, stream>>>(candV, candI, cnt, topV, topI);
    softmax_k<<<B_, 128, 0, stream>>>(topV, attn);

    // stage 4: correction MLP (bf16 MFMA) + weighted reduce
    ushort* diffB = (ushort*)big;
    ushort* hB = (ushort*)(big + (size_t)Bc * K_ * H_ * 2);
    for (int b0 = 0; b0 < B_; b0 += Bc) {
        int bcn = min(Bc, B_ - b0);
        int Mrows = bcn * K_;
        gather_diff_b<<<Mrows, 128, 0, stream>>>(xk, ckb, topI, diffB, b0);
        dim3 g1(H_ / 128, (Mrows + 127) / 128);
        gemm_nt<1, 0><<<g1, 256, 0, stream>>>(diffB, Wt1T, b_t1, nullptr, nullptr,
                                              hB, Mrows, H_, H_, H_, H_);
        gemm_nt<0, 0><<<g1, 256, 0, stream>>>(hB, Wt2T, nullptr, nullptr, nullptr,
                                              diffB, Mrows, H_, H_, H_, H_);
        reduce_ctx<<<bcn, 256, 0, stream>>>(attn, topI, labels, E_label,
                                            diffB, xe, out, b0);
    }
}

// Round 5
// 1210.543 us; speedup vs baseline: 2.0120x; 1.4799x over previous
//
#include <hip/hip_runtime.h>
#include <cfloat>
#include <cmath>

#define B_ 1024
#define D_ 256
#define H_ 512
#define N_ 100000
#define K_ 96
#define C_ 10
#define SAMP 8192      // sample columns for threshold estimation
#define CAPC 4096      // per-row candidate capacity (expected ~1170 survivors)
#define FCOLS 16384    // columns per filter block
#define FCAP 1024      // LDS staging capacity per filter block (~5x expected)

typedef __attribute__((ext_vector_type(8))) short bf16x8;
typedef __attribute__((ext_vector_type(4))) float f32x4;

__device__ __forceinline__ float bf2f(ushort h) {
    union { unsigned u; float f; } v; v.u = ((unsigned)h) << 16; return v.f;
}
__device__ __forceinline__ ushort f2bf(float f) {
    union { float f; unsigned u; } v; v.f = f;
    unsigned u = v.u;
    unsigned r = (u + 0x7fffu + ((u >> 16) & 1u)) >> 16;
    return (ushort)r;
}
// monotone fp32 -> u32 (ascending)
__device__ __forceinline__ unsigned f2key(float f) {
    unsigned u = __float_as_uint(f);
    return (u & 0x80000000u) ? ~u : (u | 0x80000000u);
}

#define GLDS(g, l)                                                            \
    __builtin_amdgcn_global_load_lds(                                         \
        (const __attribute__((address_space(1))) void*)(g),                   \
        (__attribute__((address_space(3))) void*)(l), 16, 0, 0)

// ---------------------------------------------------------------------------
// fp32 tiled GEMM (kept for tiny fp32 GEMMs: Wc, xe, xk)
// ---------------------------------------------------------------------------
template <int RELU>
__global__ __launch_bounds__(256) void gemm_nn(const float* __restrict__ A,
                                               const float* __restrict__ Bm,
                                               const float* __restrict__ bias,
                                               float* __restrict__ Cm,
                                               int M, int N, int Kd) {
    __shared__ float sA[16][68];
    __shared__ float sB[16][64];
    const int t  = threadIdx.x;
    const int tx = t & 15, ty = t >> 4;
    const int m0 = blockIdx.y * 64;
    const int n0 = blockIdx.x * 64;
    const int lr = t >> 2;
    const int lk = (t & 3) << 2;
    const int bk = t >> 4;
    const int bn = (t & 15) << 2;

    float acc[4][4] = {};
    for (int k0 = 0; k0 < Kd; k0 += 16) {
        float4 av = make_float4(0.f, 0.f, 0.f, 0.f);
        if (m0 + lr < M)
            av = *(const float4*)(A + (size_t)(m0 + lr) * Kd + k0 + lk);
        sA[lk + 0][lr] = av.x; sA[lk + 1][lr] = av.y;
        sA[lk + 2][lr] = av.z; sA[lk + 3][lr] = av.w;
        float4 bv = *(const float4*)(Bm + (size_t)(k0 + bk) * N + n0 + bn);
        *(float4*)&sB[bk][bn] = bv;
        __syncthreads();
#pragma unroll
        for (int kk = 0; kk < 16; ++kk) {
            float4 a4 = *(const float4*)&sA[kk][ty << 2];
            float4 b4 = *(const float4*)&sB[kk][tx << 2];
            float ar[4] = {a4.x, a4.y, a4.z, a4.w};
            float br[4] = {b4.x, b4.y, b4.z, b4.w};
#pragma unroll
            for (int i = 0; i < 4; ++i)
#pragma unroll
                for (int j = 0; j < 4; ++j)
                    acc[i][j] = fmaf(ar[i], br[j], acc[i][j]);
        }
        __syncthreads();
    }
#pragma unroll
    for (int i = 0; i < 4; ++i) {
        int row = m0 + (ty << 2) + i;
        if (row < M) {
            int col = n0 + (tx << 2);
            float b0 = 0.f, b1 = 0.f, b2 = 0.f, b3 = 0.f;
            if (bias) { b0 = bias[col]; b1 = bias[col + 1]; b2 = bias[col + 2]; b3 = bias[col + 3]; }
            float4 o;
            o.x = acc[i][0] + b0; o.y = acc[i][1] + b1;
            o.z = acc[i][2] + b2; o.w = acc[i][3] + b3;
            if (RELU) {
                o.x = fmaxf(o.x, 0.f); o.y = fmaxf(o.y, 0.f);
                o.z = fmaxf(o.z, 0.f); o.w = fmaxf(o.w, 0.f);
            }
            *(float4*)(Cm + (size_t)row * N + col) = o;
        }
    }
}

// ---------------------------------------------------------------------------
// bf16 MFMA NT GEMM: C = epilogue(A[M,K] @ B[N,K]^T)
// 128x128 tile, BK=32, 4 waves, each 4x4 tiles of 16x16x32 MFMA.
// SWAP=1: blockIdx.x indexes M (consecutive blocks share the B-tile).
// MODE 0: out bf16               MODE 1: +bias, relu, out bf16
// MODE 2: sim -sqrt(max(q2+c2-2acc,0)) -> fp32 Cout
// MODE 3: +bias (no relu), out bf16
// ---------------------------------------------------------------------------
template <int MODE, int SWAP>
__global__ __launch_bounds__(256) void gemm_nt(const ushort* __restrict__ A,
                                               const ushort* __restrict__ Bv,
                                               const float* __restrict__ bias,
                                               const float* __restrict__ q2v,
                                               const float* __restrict__ c2v,
                                               void* __restrict__ Cout,
                                               int M, int Nlim, int K,
                                               int ldc, int nvalid) {
    __shared__ ushort sA[128 * 32];
    __shared__ ushort sB[128 * 32];
    const int t = threadIdx.x;
    const int lane = t & 63, w = t >> 6;
    const int wm = w & 1, wn = w >> 1;
    const int m0 = (SWAP ? blockIdx.x : blockIdx.y) * 128;
    const int n0 = (SWAP ? blockIdx.y : blockIdx.x) * 128;

    f32x4 acc[4][4];
#pragma unroll
    for (int i = 0; i < 4; ++i)
#pragma unroll
        for (int j = 0; j < 4; ++j)
            acc[i][j] = (f32x4){0.f, 0.f, 0.f, 0.f};

    const int la = lane & 15, lk = lane >> 4;
    const int aoff = (wm * 64 + la) * 64 + lk * 16;
    const int boff = (wn * 64 + la) * 64 + lk * 16;
    const int r_ = t >> 2, cc_ = (t & 3);

    for (int k0 = 0; k0 < K; k0 += 32) {
#pragma unroll
        for (int q = 0; q < 2; ++q) {
            int r = r_ + q * 64;
            int ar = m0 + r; ar = (ar < M) ? ar : (M - 1);
            GLDS(A + (size_t)ar * K + k0 + cc_ * 8, (char*)sA + (q * 256 + t) * 16);
            int br = n0 + r; br = (br < Nlim) ? br : (Nlim - 1);
            GLDS(Bv + (size_t)br * K + k0 + cc_ * 8, (char*)sB + (q * 256 + t) * 16);
        }
        __syncthreads();
        bf16x8 af[4], bfr[4];
#pragma unroll
        for (int i = 0; i < 4; ++i)
            af[i] = *(const bf16x8*)((const char*)sA + aoff + i * 1024);
#pragma unroll
        for (int j = 0; j < 4; ++j)
            bfr[j] = *(const bf16x8*)((const char*)sB + boff + j * 1024);
#pragma unroll
        for (int i = 0; i < 4; ++i)
#pragma unroll
            for (int j = 0; j < 4; ++j)
                acc[i][j] = __builtin_amdgcn_mfma_f32_16x16x32_bf16(
                    af[i], bfr[j], acc[i][j], 0, 0, 0);
        __syncthreads();
    }

    const int rl = (lane >> 4) * 4, cl = lane & 15;
#pragma unroll
    for (int i = 0; i < 4; ++i) {
#pragma unroll
        for (int j = 0; j < 4; ++j) {
            int gc = n0 + wn * 64 + j * 16 + cl;
#pragma unroll
            for (int v = 0; v < 4; ++v) {
                int gr = m0 + wm * 64 + i * 16 + rl + v;
                if (gr < M && gc < nvalid) {
                    float val = acc[i][j][v];
                    if (MODE == 2) {
                        float d2 = q2v[gr] + c2v[gc] - 2.f * val;
                        ((float*)Cout)[(size_t)gr * ldc + gc] = -sqrtf(fmaxf(d2, 0.f));
                    } else {
                        if (MODE == 1 || MODE == 3) val += bias[gc];
                        if (MODE == 1) val = fmaxf(val, 0.f);
                        ((ushort*)Cout)[(size_t)gr * ldc + gc] = f2bf(val);
                    }
                }
            }
        }
    }
}

// ---------------------------------------------------------------------------
// per-row radix-select of the 96th-largest over the first SAMP columns
// ---------------------------------------------------------------------------
__global__ __launch_bounds__(256) void thr_select(const float* __restrict__ S,
                                                  int ld,
                                                  float* __restrict__ thrArr) {
    __shared__ unsigned keys[SAMP];
    __shared__ int hist[256];
    __shared__ int sel[2];
    const int b = blockIdx.x, t = threadIdx.x;
    for (int i = t; i < SAMP; i += 256)
        keys[i] = f2key(S[(size_t)b * ld + i]);
    __syncthreads();
    unsigned prefix = 0, mask = 0;
    int rank = K_;
    for (int shift = 24; shift >= 0; shift -= 8) {
        hist[t & 255] = 0;
        __syncthreads();
        for (int i = t; i < SAMP; i += 256) {
            unsigned k = keys[i];
            if ((k & mask) == prefix) atomicAdd(&hist[(k >> shift) & 255], 1);
        }
        __syncthreads();
        if (t == 0) {
            int r = rank, d = 255;
            for (; d > 0; --d) { int c = hist[d]; if (r - c <= 0) break; r -= c; }
            sel[0] = d; sel[1] = (r < 1) ? 1 : r;
        }
        __syncthreads();
        prefix |= ((unsigned)sel[0]) << shift;
        rank = sel[1];
        mask |= (0xFFu << shift);
        __syncthreads();
    }
    if (t == 0) {
        unsigned u = prefix;
        unsigned f = (u & 0x80000000u) ? (u & 0x7FFFFFFFu) : ~u;
        thrArr[b] = __uint_as_float(f);
    }
}

// ---------------------------------------------------------------------------
// streaming threshold filter: one block per (FCOLS segment, row).
// Survivors staged in LDS (LDS atomics only), ONE global atomic per block,
// then coalesced copy-out. Eliminates per-take global atomic round-trips.
// ---------------------------------------------------------------------------
__global__ __launch_bounds__(256) void filter_sim(const float* __restrict__ S,
                                                  int ld, int ncols, int j0,
                                                  const float* __restrict__ thrArr,
                                                  float* __restrict__ candV,
                                                  int* __restrict__ candI,
                                                  int* __restrict__ cnt) {
    __shared__ float lv[FCAP];
    __shared__ int   li[FCAP];
    __shared__ int   ln;
    __shared__ int   gbase;
    const int b = blockIdx.y;
    const float thr = thrArr[b];
    const float* row = S + (size_t)b * ld;
    if (threadIdx.x == 0) ln = 0;
    __syncthreads();
    const int cbase = blockIdx.x * FCOLS;
    const int cend = min(cbase + FCOLS, ncols);   // ncols % 4 == 0 (100000%4==0)
    for (int c = cbase + threadIdx.x * 4; c < cend; c += 1024) {
        float4 v4 = *(const float4*)(row + c);
        float vv[4] = {v4.x, v4.y, v4.z, v4.w};
#pragma unroll
        for (int e = 0; e < 4; ++e) {
            if (vv[e] >= thr) {
                int p = atomicAdd(&ln, 1);
                if (p < FCAP) { lv[p] = vv[e]; li[p] = j0 + c + e; }
            }
        }
    }
    __syncthreads();
    int n = ln; if (n > FCAP) n = FCAP;
    if (threadIdx.x == 0) gbase = atomicAdd(&cnt[b], n);
    __syncthreads();
    const int gb = gbase;
    for (int i = threadIdx.x; i < n; i += 256) {
        int pos = gb + i;
        if (pos < CAPC) {
            candV[(size_t)b * CAPC + pos] = lv[i];
            candI[(size_t)b * CAPC + pos] = li[i];
        }
    }
}

// ---------------------------------------------------------------------------
// per-row exact top-96 from candidate buffer via radix select + compaction
// ---------------------------------------------------------------------------
__global__ __launch_bounds__(256) void final_select(const float* __restrict__ candV,
                                                    const int* __restrict__ candI,
                                                    const int* __restrict__ cnt,
                                                    float* __restrict__ topV,
                                                    int* __restrict__ topI) {
    __shared__ unsigned keys[CAPC];
    __shared__ int hist[256];
    __shared__ int sel[2];
    __shared__ int poscnt, eqcnt;
    const int b = blockIdx.x, t = threadIdx.x;
    int n = cnt[b]; if (n > CAPC) n = CAPC;
    for (int i = t; i < n; i += 256)
        keys[i] = f2key(candV[(size_t)b * CAPC + i]);
    __syncthreads();
    unsigned prefix = 0, mask = 0;
    int rank = K_;
    for (int shift = 24; shift >= 0; shift -= 8) {
        hist[t & 255] = 0;
        __syncthreads();
        for (int i = t; i < n; i += 256) {
            unsigned k = keys[i];
            if ((k & mask) == prefix) atomicAdd(&hist[(k >> shift) & 255], 1);
        }
        __syncthreads();
        if (t == 0) {
            int r = rank, d = 255;
            for (; d > 0; --d) { int c = hist[d]; if (r - c <= 0) break; r -= c; }
            sel[0] = d; sel[1] = (r < 1) ? 1 : r;
        }
        __syncthreads();
        prefix |= ((unsigned)sel[0]) << shift;
        rank = sel[1];
        mask |= (0xFFu << shift);
        __syncthreads();
    }
    unsigned kth = prefix;
    if (t == 0) { poscnt = 0; eqcnt = 0; }
    __syncthreads();
    for (int i = t; i < n; i += 256) {
        if (keys[i] > kth) {
            int p = atomicAdd(&poscnt, 1);
            topV[b * K_ + p] = candV[(size_t)b * CAPC + i];
            topI[b * K_ + p] = candI[(size_t)b * CAPC + i];
        }
    }
    __syncthreads();
    int base = poscnt;
    for (int i = t; i < n; i += 256) {
        if (keys[i] == kth) {
            int p = atomicAdd(&eqcnt, 1);
            if (base + p < K_) {
                topV[b * K_ + base + p] = candV[(size_t)b * CAPC + i];
                topI[b * K_ + base + p] = candI[(size_t)b * CAPC + i];
            }
        }
    }
}

__global__ void init_cnt(int* cnt) {
    int i = blockIdx.x * 256 + threadIdx.x;
    if (i < B_) cnt[i] = 0;
}

// ---------------------------------------------------------------------------
__global__ void conv_f2b(const float* __restrict__ in, ushort* __restrict__ out, int n) {
    int i = (blockIdx.x * 256 + threadIdx.x) * 4;
    int stride = gridDim.x * 256 * 4;
    for (; i < n; i += stride) {
        float4 v = *(const float4*)(in + i);
        ushort4 o;
        o.x = f2bf(v.x); o.y = f2bf(v.y); o.z = f2bf(v.z); o.w = f2bf(v.w);
        *(ushort4*)(out + i) = o;
    }
}

__global__ __launch_bounds__(256) void transpose_f2b(const float* __restrict__ in,
                                                     ushort* __restrict__ out,
                                                     int R, int Cn) {
    __shared__ float tile[32][33];
    int bx = blockIdx.x * 32, by = blockIdx.y * 32;
    int tx = threadIdx.x & 31, ty = threadIdx.x >> 5;
    int x = bx + tx;
#pragma unroll
    for (int dy = 0; dy < 32; dy += 8) {
        int y = by + ty + dy;
        if (x < Cn && y < R) tile[ty + dy][tx] = in[(size_t)y * Cn + x];
    }
    __syncthreads();
    int ox = by + tx;
#pragma unroll
    for (int dy = 0; dy < 32; dy += 8) {
        int oy = bx + ty + dy;
        if (ox < R && oy < Cn) out[(size_t)oy * R + ox] = f2bf(tile[tx][ty + dy]);
    }
}

__global__ __launch_bounds__(64) void rowsq_b(const ushort* __restrict__ X,
                                              float* __restrict__ outv) {
    const int r = blockIdx.x, t = threadIdx.x;
    const ushort* p = X + (size_t)r * H_;
    ushort4 a = *(const ushort4*)(p + t * 4);
    ushort4 b = *(const ushort4*)(p + 256 + t * 4);
    float ax = bf2f(a.x), ay = bf2f(a.y), az = bf2f(a.z), aw = bf2f(a.w);
    float bx = bf2f(b.x), by = bf2f(b.y), bz = bf2f(b.z), bw = bf2f(b.w);
    float v = ax * ax + ay * ay + az * az + aw * aw +
              bx * bx + by * by + bz * bz + bw * bw;
    for (int off = 32; off > 0; off >>= 1) v += __shfl_down(v, off);
    if (t == 0) outv[r] = v;
}

__global__ void bcomb_k(const float* __restrict__ b_enc,
                        const float* __restrict__ W_key,
                        const float* __restrict__ b_key,
                        float* __restrict__ b_comb) {
    int h = blockIdx.x * 256 + threadIdx.x;
    if (h >= H_) return;
    float acc = b_key[h];
    for (int m = 0; m < H_; ++m)
        acc = fmaf(b_enc[m], W_key[(size_t)m * H_ + h], acc);
    b_comb[h] = acc;
}

__global__ __launch_bounds__(128) void softmax_k(const float* __restrict__ topVal,
                                                 float* __restrict__ attn) {
    __shared__ float red[128];
    const int b = blockIdx.x, t = threadIdx.x;
    float v = (t < K_) ? topVal[b * K_ + t] : -FLT_MAX;
    red[t] = v; __syncthreads();
    for (int s = 64; s > 0; s >>= 1) {
        if (t < s) red[t] = fmaxf(red[t], red[t + s]);
        __syncthreads();
    }
    float m = red[0]; __syncthreads();
    float e = (t < K_) ? expf(v - m) : 0.f;
    red[t] = e; __syncthreads();
    for (int s = 64; s > 0; s >>= 1) {
        if (t < s) red[t] += red[t + s];
        __syncthreads();
    }
    float ssum = red[0];
    if (t < K_) attn[b * K_ + t] = e / ssum;
}

__global__ __launch_bounds__(128) void gather_diff_b(const float* __restrict__ XK,
                                                     const ushort* __restrict__ CK,
                                                     const int* __restrict__ topI,
                                                     ushort* __restrict__ diff,
                                                     int b0) {
    const int r = blockIdx.x;
    const int b = b0 + r / K_;
    const int idx = topI[b * K_ + (r % K_)];
    const int t = threadIdx.x;
    float4 xv = *(const float4*)(XK + (size_t)b * H_ + t * 4);
    ushort4 cv = *(const ushort4*)(CK + (size_t)idx * H_ + t * 4);
    ushort4 o;
    o.x = f2bf(xv.x - bf2f(cv.x));
    o.y = f2bf(xv.y - bf2f(cv.y));
    o.z = f2bf(xv.z - bf2f(cv.z));
    o.w = f2bf(xv.w - bf2f(cv.w));
    *(ushort4*)(diff + (size_t)r * H_ + t * 4) = o;
}

__global__ __launch_bounds__(256) void reduce_ctx(const float* __restrict__ attn,
                                                  const int* __restrict__ topI,
                                                  const int* __restrict__ labels,
                                                  const float* __restrict__ E,
                                                  const ushort* __restrict__ tout,
                                                  const float* __restrict__ xe,
                                                  float* __restrict__ out, int b0) {
    const int bl = blockIdx.x;
    const int b = b0 + bl;
    const int t = threadIdx.x;
    float a0 = 0.f, a1 = 0.f;
    for (int k = 0; k < K_; ++k) {
        float w = attn[b * K_ + k];
        int idx = topI[b * K_ + k];
        int lab = labels[idx];
        const float* el = E + (size_t)lab * H_;
        const ushort* tr = tout + (size_t)(bl * K_ + k) * H_;
        a0 = fmaf(w, el[t] + bf2f(tr[t]), a0);
        a1 = fmaf(w, el[t + 256] + bf2f(tr[t + 256]), a1);
    }
    out[(size_t)b * H_ + t]       = xe[(size_t)b * H_ + t] + a0;
    out[(size_t)b * H_ + t + 256] = xe[(size_t)b * H_ + t + 256] + a1;
}

// ---------------------------------------------------------------------------
extern "C" void kernel_launch(void* const* d_in, const int* in_sizes, int n_in,
                              void* d_out, int out_size, void* d_ws, size_t ws_size,
                              hipStream_t stream) {
    const float* x      = (const float*)d_in[0];
    const float* cx     = (const float*)d_in[1];
    const int*   labels = (const int*)d_in[2];
    const float* W_enc  = (const float*)d_in[3];
    const float* b_enc  = (const float*)d_in[4];
    const float* W_key  = (const float*)d_in[5];
    const float* b_key  = (const float*)d_in[6];
    // d_in[7]=W_val, d_in[8]=b_val dead (gather unused in reference)
    const float* E_label = (const float*)d_in[9];
    const float* W_t1   = (const float*)d_in[10];
    const float* b_t1   = (const float*)d_in[11];
    const float* W_t2   = (const float*)d_in[12];
    float* out = (float*)d_out;

    char* base = (char*)d_ws;
    size_t off = 0;
    auto take = [&](size_t n) -> char* {
        char* p = base + off;
        off = (off + n + 255) & ~(size_t)255;
        return p;
    };
    float*  Wc    = (float*)take((size_t)D_ * H_ * 4);
    float*  bc    = (float*)take((size_t)H_ * 4);
    ushort* WcT   = (ushort*)take((size_t)H_ * D_ * 2);
    ushort* Wt1T  = (ushort*)take((size_t)H_ * H_ * 2);
    ushort* Wt2T  = (ushort*)take((size_t)H_ * H_ * 2);
    float*  xe    = (float*)take((size_t)B_ * H_ * 4);
    float*  xk    = (float*)take((size_t)B_ * H_ * 4);
    ushort* xkb   = (ushort*)take((size_t)B_ * H_ * 2);
    float*  q2    = (float*)take((size_t)B_ * 4);
    ushort* ckb   = (ushort*)take((size_t)N_ * H_ * 2);
    float*  c2    = (float*)take((size_t)N_ * 4);
    float*  topV  = (float*)take((size_t)B_ * K_ * 4);
    int*    topI  = (int*)take((size_t)B_ * K_ * 4);
    float*  thr   = (float*)take((size_t)B_ * 4);
    float*  attn  = (float*)take((size_t)B_ * K_ * 4);
    int*    cnt   = (int*)take((size_t)B_ * 4);
    float*  candV = (float*)take((size_t)B_ * CAPC * 4);
    int*    candI = (int*)take((size_t)B_ * CAPC * 4);
    char*   big   = base + off;      // shared: cxb -> simBuf -> stage4 bufs
    size_t rem = (ws_size > off) ? (ws_size - off) : 0;

    ushort* cxb    = (ushort*)big;   // N*D*2 = 51.2 MB (dead after stage 2)
    float*  simBuf = (float*)big;    // B*Nc0*4

    long long nc = (long long)((rem / ((size_t)B_ * 4)) & ~(size_t)127);
    if (nc > 25600) nc = 25600;      // ~100 MB chunk: stays mostly in L3 for filter
    if (nc < SAMP) nc = SAMP;        // thr_select reads first SAMP cols of chunk 0
    int Nc0 = (int)nc;

    long long bcq = (long long)(rem / ((size_t)K_ * H_ * 2 * 2));
    if (bcq > B_) bcq = B_;
    if (bcq < 1) bcq = 1;
    int Bc = (int)bcq;

    // stage 0: combined candidate weights + transposed bf16 weights
    {
        dim3 g(H_ / 64, D_ / 64);
        gemm_nn<0><<<g, 256, 0, stream>>>(W_enc, W_key, nullptr, Wc, D_, H_, H_);
        bcomb_k<<<(H_ + 255) / 256, 256, 0, stream>>>(b_enc, W_key, b_key, bc);
        dim3 gt1((H_ + 31) / 32, (D_ + 31) / 32);
        transpose_f2b<<<gt1, 256, 0, stream>>>(Wc, WcT, D_, H_);
        dim3 gt2((H_ + 31) / 32, (H_ + 31) / 32);
        transpose_f2b<<<gt2, 256, 0, stream>>>(W_t1, Wt1T, H_, H_);
        transpose_f2b<<<gt2, 256, 0, stream>>>(W_t2, Wt2T, H_, H_);
    }
    // stage 1: query encodes (fp32, tiny) + bf16 conversions
    {
        dim3 gx(H_ / 64, B_ / 64);
        gemm_nn<0><<<gx, 256, 0, stream>>>(x, W_enc, b_enc, xe, B_, H_, D_);
        gemm_nn<0><<<gx, 256, 0, stream>>>(x, Wc, bc, xk, B_, H_, D_);
        conv_f2b<<<1024, 256, 0, stream>>>(xk, xkb, B_ * H_);
        conv_f2b<<<2048, 256, 0, stream>>>(cx, cxb, N_ * D_);
    }
    // stage 2: candidate keys via bf16 MFMA (bias, no relu)
    {
        dim3 g(H_ / 128, (N_ + 127) / 128);
        gemm_nt<3, 0><<<g, 256, 0, stream>>>(cxb, WcT, bc, nullptr, nullptr,
                                             ckb, N_, H_, D_, H_, H_);
    }
    rowsq_b<<<N_, 64, 0, stream>>>(ckb, c2);
    rowsq_b<<<B_, 64, 0, stream>>>(xkb, q2);

    // stage 3: chunked sim GEMM -> (chunk 0: threshold) -> LDS-staged filter
    init_cnt<<<(B_ + 255) / 256, 256, 0, stream>>>(cnt);
    for (int j0 = 0; j0 < N_; j0 += Nc0) {
        int ncols = min(Nc0, N_ - j0);
        dim3 g(B_ / 128, (ncols + 127) / 128);   // SWAP=1: x=M so B-tile shared
        gemm_nt<2, 1><<<g, 256, 0, stream>>>(xkb, ckb + (size_t)j0 * H_, nullptr,
                                             q2, c2 + j0, simBuf,
                                             B_, N_ - j0, H_, Nc0, ncols);
        if (j0 == 0)
            thr_select<<<B_, 256, 0, stream>>>(simBuf, Nc0, thr);
        dim3 gf((ncols + FCOLS - 1) / FCOLS, B_);
        filter_sim<<<gf, 256, 0, stream>>>(simBuf, Nc0, ncols, j0, thr,
                                           candV, candI, cnt);
    }
    final_select<<<B_, 256, 0, stream>>>(candV, candI, cnt, topV, topI);
    softmax_k<<<B_, 128, 0, stream>>>(topV, attn);

    // stage 4: correction MLP (bf16 MFMA) + weighted reduce
    ushort* diffB = (ushort*)big;
    ushort* hB = (ushort*)(big + (size_t)Bc * K_ * H_ * 2);
    for (int b0 = 0; b0 < B_; b0 += Bc) {
        int bcn = min(Bc, B_ - b0);
        int Mrows = bcn * K_;
        gather_diff_b<<<Mrows, 128, 0, stream>>>(xk, ckb, topI, diffB, b0);
        dim3 g1(H_ / 128, (Mrows + 127) / 128);
        gemm_nt<1, 0><<<g1, 256, 0, stream>>>(diffB, Wt1T, b_t1, nullptr, nullptr,
                                              hB, Mrows, H_, H_, H_, H_);
        gemm_nt<0, 0><<<g1, 256, 0, stream>>>(hB, Wt2T, nullptr, nullptr, nullptr,
                                              diffB, Mrows, H_, H_, H_, H_);
        reduce_ctx<<<bcn, 256, 0, stream>>>(attn, topI, labels, E_label,
                                            diffB, xe, out, b0);
    }
}

// Round 6
// 1070.957 us; speedup vs baseline: 2.2742x; 1.1303x over previous
//
#include <hip/hip_runtime.h>
#include <cfloat>
#include <cmath>

#define B_ 1024
#define D_ 256
#define H_ 512
#define N_ 100000
#define K_ 96
#define C_ 10
#define SAMP 8192      // sample columns for threshold estimation
#define CAPC 4096      // per-row candidate capacity (expected ~1170 survivors)
#define FCOLS 16384    // columns per filter block
#define FCAP 1024      // LDS staging capacity per filter block (~5x expected)

typedef __attribute__((ext_vector_type(8))) short bf16x8;
typedef __attribute__((ext_vector_type(4))) float f32x4;

__device__ __forceinline__ float bf2f(ushort h) {
    union { unsigned u; float f; } v; v.u = ((unsigned)h) << 16; return v.f;
}
__device__ __forceinline__ ushort f2bf(float f) {
    union { float f; unsigned u; } v; v.f = f;
    unsigned u = v.u;
    unsigned r = (u + 0x7fffu + ((u >> 16) & 1u)) >> 16;
    return (ushort)r;
}
// monotone fp32 -> u32 (ascending)
__device__ __forceinline__ unsigned f2key(float f) {
    unsigned u = __float_as_uint(f);
    return (u & 0x80000000u) ? ~u : (u | 0x80000000u);
}
// d^2 from raw dot product -- MUST be the single definition used by both
// thr_select and filter_sim so chunk-0 recompute is bitwise identical.
__device__ __forceinline__ float d2_of(float acc, float q2, float c2) {
    return fmaxf(fmaf(-2.f, acc, q2 + c2), 0.f);
}

#define GLDS(g, l)                                                            \
    __builtin_amdgcn_global_load_lds(                                         \
        (const __attribute__((address_space(1))) void*)(g),                   \
        (__attribute__((address_space(3))) void*)(l), 16, 0, 0)

// ---------------------------------------------------------------------------
// fp32 tiled GEMM (kept for tiny fp32 GEMMs: Wc, xe, xk)
// ---------------------------------------------------------------------------
template <int RELU>
__global__ __launch_bounds__(256) void gemm_nn(const float* __restrict__ A,
                                               const float* __restrict__ Bm,
                                               const float* __restrict__ bias,
                                               float* __restrict__ Cm,
                                               int M, int N, int Kd) {
    __shared__ float sA[16][68];
    __shared__ float sB[16][64];
    const int t  = threadIdx.x;
    const int tx = t & 15, ty = t >> 4;
    const int m0 = blockIdx.y * 64;
    const int n0 = blockIdx.x * 64;
    const int lr = t >> 2;
    const int lk = (t & 3) << 2;
    const int bk = t >> 4;
    const int bn = (t & 15) << 2;

    float acc[4][4] = {};
    for (int k0 = 0; k0 < Kd; k0 += 16) {
        float4 av = make_float4(0.f, 0.f, 0.f, 0.f);
        if (m0 + lr < M)
            av = *(const float4*)(A + (size_t)(m0 + lr) * Kd + k0 + lk);
        sA[lk + 0][lr] = av.x; sA[lk + 1][lr] = av.y;
        sA[lk + 2][lr] = av.z; sA[lk + 3][lr] = av.w;
        float4 bv = *(const float4*)(Bm + (size_t)(k0 + bk) * N + n0 + bn);
        *(float4*)&sB[bk][bn] = bv;
        __syncthreads();
#pragma unroll
        for (int kk = 0; kk < 16; ++kk) {
            float4 a4 = *(const float4*)&sA[kk][ty << 2];
            float4 b4 = *(const float4*)&sB[kk][tx << 2];
            float ar[4] = {a4.x, a4.y, a4.z, a4.w};
            float br[4] = {b4.x, b4.y, b4.z, b4.w};
#pragma unroll
            for (int i = 0; i < 4; ++i)
#pragma unroll
                for (int j = 0; j < 4; ++j)
                    acc[i][j] = fmaf(ar[i], br[j], acc[i][j]);
        }
        __syncthreads();
    }
#pragma unroll
    for (int i = 0; i < 4; ++i) {
        int row = m0 + (ty << 2) + i;
        if (row < M) {
            int col = n0 + (tx << 2);
            float b0 = 0.f, b1 = 0.f, b2 = 0.f, b3 = 0.f;
            if (bias) { b0 = bias[col]; b1 = bias[col + 1]; b2 = bias[col + 2]; b3 = bias[col + 3]; }
            float4 o;
            o.x = acc[i][0] + b0; o.y = acc[i][1] + b1;
            o.z = acc[i][2] + b2; o.w = acc[i][3] + b3;
            if (RELU) {
                o.x = fmaxf(o.x, 0.f); o.y = fmaxf(o.y, 0.f);
                o.z = fmaxf(o.z, 0.f); o.w = fmaxf(o.w, 0.f);
            }
            *(float4*)(Cm + (size_t)row * N + col) = o;
        }
    }
}

// ---------------------------------------------------------------------------
// bf16 MFMA NT GEMM: C = epilogue(A[M,K] @ B[N,K]^T)
// 128x128 tile, BK=32, 4 waves, each 4x4 tiles of 16x16x32 MFMA.
// SWZ=0: 2-D grid (x=N-tiles, y=M-tiles).
// SWZ=1: 1-D grid, XCD-swizzled so the 8 M-tiles sharing one B/N-tile run on
//        ONE XCD (B-tile fetched once into that XCD's L2). `per` = N-tiles/XCD.
//        Requires M == 1024 (8 M-tiles).
// SWZ=2: 1-D grid, XCD-swizzled so the 4 N-tiles sharing one A/M-tile run on
//        one XCD. `per` = M-tiles/XCD. Requires Nlim == 512 (4 N-tiles).
// MODE 0: out bf16     MODE 1: +bias, relu, out bf16
// MODE 2: raw dot product -> fp32 Cout (sim; -sqrt deferred downstream)
// MODE 3: +bias (no relu), out bf16
// ---------------------------------------------------------------------------
template <int MODE, int SWZ>
__global__ __launch_bounds__(256) void gemm_nt(const ushort* __restrict__ A,
                                               const ushort* __restrict__ Bv,
                                               const float* __restrict__ bias,
                                               void* __restrict__ Cout,
                                               int M, int Nlim, int K,
                                               int ldc, int nvalid, int per) {
    int m0, n0;
    if (SWZ == 0) {
        m0 = blockIdx.y * 128; n0 = blockIdx.x * 128;
    } else if (SWZ == 1) {
        int bid = blockIdx.x;
        int xcd = bid & 7, slot = bid >> 3;
        m0 = (slot & 7) * 128;
        n0 = (xcd * per + (slot >> 3)) * 128;
        if (n0 >= nvalid || m0 >= M) return;
    } else {
        int bid = blockIdx.x;
        int xcd = bid & 7, slot = bid >> 3;
        n0 = (slot & 3) * 128;
        m0 = (xcd * per + (slot >> 2)) * 128;
        if (m0 >= M) return;
    }

    __shared__ ushort sA[128 * 32];
    __shared__ ushort sB[128 * 32];
    const int t = threadIdx.x;
    const int lane = t & 63, w = t >> 6;
    const int wm = w & 1, wn = w >> 1;

    f32x4 acc[4][4];
#pragma unroll
    for (int i = 0; i < 4; ++i)
#pragma unroll
        for (int j = 0; j < 4; ++j)
            acc[i][j] = (f32x4){0.f, 0.f, 0.f, 0.f};

    const int la = lane & 15, lk = lane >> 4;
    const int aoff = (wm * 64 + la) * 64 + lk * 16;
    const int boff = (wn * 64 + la) * 64 + lk * 16;
    const int r_ = t >> 2, cc_ = (t & 3);

    for (int k0 = 0; k0 < K; k0 += 32) {
#pragma unroll
        for (int q = 0; q < 2; ++q) {
            int r = r_ + q * 64;
            int ar = m0 + r; ar = (ar < M) ? ar : (M - 1);
            GLDS(A + (size_t)ar * K + k0 + cc_ * 8, (char*)sA + (q * 256 + t) * 16);
            int br = n0 + r; br = (br < Nlim) ? br : (Nlim - 1);
            GLDS(Bv + (size_t)br * K + k0 + cc_ * 8, (char*)sB + (q * 256 + t) * 16);
        }
        __syncthreads();
        bf16x8 af[4], bfr[4];
#pragma unroll
        for (int i = 0; i < 4; ++i)
            af[i] = *(const bf16x8*)((const char*)sA + aoff + i * 1024);
#pragma unroll
        for (int j = 0; j < 4; ++j)
            bfr[j] = *(const bf16x8*)((const char*)sB + boff + j * 1024);
#pragma unroll
        for (int i = 0; i < 4; ++i)
#pragma unroll
            for (int j = 0; j < 4; ++j)
                acc[i][j] = __builtin_amdgcn_mfma_f32_16x16x32_bf16(
                    af[i], bfr[j], acc[i][j], 0, 0, 0);
        __syncthreads();
    }

    const int rl = (lane >> 4) * 4, cl = lane & 15;
#pragma unroll
    for (int i = 0; i < 4; ++i) {
#pragma unroll
        for (int j = 0; j < 4; ++j) {
            int gc = n0 + wn * 64 + j * 16 + cl;
#pragma unroll
            for (int v = 0; v < 4; ++v) {
                int gr = m0 + wm * 64 + i * 16 + rl + v;
                if (gr < M && gc < nvalid) {
                    float val = acc[i][j][v];
                    if (MODE == 2) {
                        ((float*)Cout)[(size_t)gr * ldc + gc] = val;
                    } else {
                        if (MODE == 1 || MODE == 3) val += bias[gc];
                        if (MODE == 1) val = fmaxf(val, 0.f);
                        ((ushort*)Cout)[(size_t)gr * ldc + gc] = f2bf(val);
                    }
                }
            }
        }
    }
}

// ---------------------------------------------------------------------------
// per-row radix-select of the 96th-SMALLEST d^2 over the first SAMP columns.
// S holds raw dot products; d^2 built on the fly. Keys inverted (~f2key) so
// "k-th largest key" == "k-th smallest d^2".
// ---------------------------------------------------------------------------
__global__ __launch_bounds__(256) void thr_select(const float* __restrict__ S,
                                                  int ld,
                                                  const float* __restrict__ q2v,
                                                  const float* __restrict__ c2v,
                                                  float* __restrict__ thrArr) {
    __shared__ unsigned keys[SAMP];
    __shared__ int hist[256];
    __shared__ int sel[2];
    const int b = blockIdx.x, t = threadIdx.x;
    const float q2b = q2v[b];
    for (int i = t; i < SAMP; i += 256)
        keys[i] = ~f2key(d2_of(S[(size_t)b * ld + i], q2b, c2v[i]));
    __syncthreads();
    unsigned prefix = 0, mask = 0;
    int rank = K_;
    for (int shift = 24; shift >= 0; shift -= 8) {
        hist[t & 255] = 0;
        __syncthreads();
        for (int i = t; i < SAMP; i += 256) {
            unsigned k = keys[i];
            if ((k & mask) == prefix) atomicAdd(&hist[(k >> shift) & 255], 1);
        }
        __syncthreads();
        if (t == 0) {
            int r = rank, d = 255;
            for (; d > 0; --d) { int c = hist[d]; if (r - c <= 0) break; r -= c; }
            sel[0] = d; sel[1] = (r < 1) ? 1 : r;
        }
        __syncthreads();
        prefix |= ((unsigned)sel[0]) << shift;
        rank = sel[1];
        mask |= (0xFFu << shift);
        __syncthreads();
    }
    if (t == 0) {
        // decode: key of 96th-smallest d2 (d2>=0 so sign bit of f2key is set)
        unsigned key = ~prefix;
        thrArr[b] = __uint_as_float(key & 0x7FFFFFFFu);
    }
}

// ---------------------------------------------------------------------------
// streaming threshold filter over the raw-dot sim chunk: survivors are
// d2 <= thr2[row]. LDS staging, ONE global atomic per block, coalesced
// copy-out. candV stores d2 (clamped).
// ---------------------------------------------------------------------------
__global__ __launch_bounds__(256) void filter_sim(const float* __restrict__ S,
                                                  int ld, int ncols, int j0,
                                                  const float* __restrict__ q2v,
                                                  const float* __restrict__ c2j,
                                                  const float* __restrict__ thrArr,
                                                  float* __restrict__ candV,
                                                  int* __restrict__ candI,
                                                  int* __restrict__ cnt) {
    __shared__ float lv[FCAP];
    __shared__ int   li[FCAP];
    __shared__ int   ln;
    __shared__ int   gbase;
    const int b = blockIdx.y;
    const float thr2 = thrArr[b];
    const float q2b = q2v[b];
    const float* row = S + (size_t)b * ld;
    if (threadIdx.x == 0) ln = 0;
    __syncthreads();
    const int cbase = blockIdx.x * FCOLS;
    const int cend = min(cbase + FCOLS, ncols);   // ncols % 4 == 0 (100000%4==0)
    for (int c = cbase + threadIdx.x * 4; c < cend; c += 1024) {
        float4 a4 = *(const float4*)(row + c);
        float4 c4 = *(const float4*)(c2j + c);
        float dv[4];
        dv[0] = d2_of(a4.x, q2b, c4.x);
        dv[1] = d2_of(a4.y, q2b, c4.y);
        dv[2] = d2_of(a4.z, q2b, c4.z);
        dv[3] = d2_of(a4.w, q2b, c4.w);
#pragma unroll
        for (int e = 0; e < 4; ++e) {
            if (dv[e] <= thr2) {
                int p = atomicAdd(&ln, 1);
                if (p < FCAP) { lv[p] = dv[e]; li[p] = j0 + c + e; }
            }
        }
    }
    __syncthreads();
    int n = ln; if (n > FCAP) n = FCAP;
    if (threadIdx.x == 0) gbase = atomicAdd(&cnt[b], n);
    __syncthreads();
    const int gb = gbase;
    for (int i = threadIdx.x; i < n; i += 256) {
        int pos = gb + i;
        if (pos < CAPC) {
            candV[(size_t)b * CAPC + pos] = lv[i];
            candI[(size_t)b * CAPC + pos] = li[i];
        }
    }
}

// ---------------------------------------------------------------------------
// per-row exact 96-smallest-d2 from candidate buffer via radix select
// (inverted keys) + compaction. topV receives d2.
// ---------------------------------------------------------------------------
__global__ __launch_bounds__(256) void final_select(const float* __restrict__ candV,
                                                    const int* __restrict__ candI,
                                                    const int* __restrict__ cnt,
                                                    float* __restrict__ topV,
                                                    int* __restrict__ topI) {
    __shared__ unsigned keys[CAPC];
    __shared__ int hist[256];
    __shared__ int sel[2];
    __shared__ int poscnt, eqcnt;
    const int b = blockIdx.x, t = threadIdx.x;
    int n = cnt[b]; if (n > CAPC) n = CAPC;
    for (int i = t; i < n; i += 256)
        keys[i] = ~f2key(candV[(size_t)b * CAPC + i]);
    __syncthreads();
    unsigned prefix = 0, mask = 0;
    int rank = K_;
    for (int shift = 24; shift >= 0; shift -= 8) {
        hist[t & 255] = 0;
        __syncthreads();
        for (int i = t; i < n; i += 256) {
            unsigned k = keys[i];
            if ((k & mask) == prefix) atomicAdd(&hist[(k >> shift) & 255], 1);
        }
        __syncthreads();
        if (t == 0) {
            int r = rank, d = 255;
            for (; d > 0; --d) { int c = hist[d]; if (r - c <= 0) break; r -= c; }
            sel[0] = d; sel[1] = (r < 1) ? 1 : r;
        }
        __syncthreads();
        prefix |= ((unsigned)sel[0]) << shift;
        rank = sel[1];
        mask |= (0xFFu << shift);
        __syncthreads();
    }
    unsigned kth = prefix;
    if (t == 0) { poscnt = 0; eqcnt = 0; }
    __syncthreads();
    for (int i = t; i < n; i += 256) {
        if (keys[i] > kth) {
            int p = atomicAdd(&poscnt, 1);
            topV[b * K_ + p] = candV[(size_t)b * CAPC + i];
            topI[b * K_ + p] = candI[(size_t)b * CAPC + i];
        }
    }
    __syncthreads();
    int base = poscnt;
    for (int i = t; i < n; i += 256) {
        if (keys[i] == kth) {
            int p = atomicAdd(&eqcnt, 1);
            if (base + p < K_) {
                topV[b * K_ + base + p] = candV[(size_t)b * CAPC + i];
                topI[b * K_ + base + p] = candI[(size_t)b * CAPC + i];
            }
        }
    }
}

__global__ void init_cnt(int* cnt) {
    int i = blockIdx.x * 256 + threadIdx.x;
    if (i < B_) cnt[i] = 0;
}

// ---------------------------------------------------------------------------
__global__ void conv_f2b(const float* __restrict__ in, ushort* __restrict__ out, int n) {
    int i = (blockIdx.x * 256 + threadIdx.x) * 4;
    int stride = gridDim.x * 256 * 4;
    for (; i < n; i += stride) {
        float4 v = *(const float4*)(in + i);
        ushort4 o;
        o.x = f2bf(v.x); o.y = f2bf(v.y); o.z = f2bf(v.z); o.w = f2bf(v.w);
        *(ushort4*)(out + i) = o;
    }
}

__global__ __launch_bounds__(256) void transpose_f2b(const float* __restrict__ in,
                                                     ushort* __restrict__ out,
                                                     int R, int Cn) {
    __shared__ float tile[32][33];
    int bx = blockIdx.x * 32, by = blockIdx.y * 32;
    int tx = threadIdx.x & 31, ty = threadIdx.x >> 5;
    int x = bx + tx;
#pragma unroll
    for (int dy = 0; dy < 32; dy += 8) {
        int y = by + ty + dy;
        if (x < Cn && y < R) tile[ty + dy][tx] = in[(size_t)y * Cn + x];
    }
    __syncthreads();
    int ox = by + tx;
#pragma unroll
    for (int dy = 0; dy < 32; dy += 8) {
        int oy = bx + ty + dy;
        if (ox < R && oy < Cn) out[(size_t)oy * R + ox] = f2bf(tile[tx][ty + dy]);
    }
}

__global__ __launch_bounds__(64) void rowsq_b(const ushort* __restrict__ X,
                                              float* __restrict__ outv) {
    const int r = blockIdx.x, t = threadIdx.x;
    const ushort* p = X + (size_t)r * H_;
    ushort4 a = *(const ushort4*)(p + t * 4);
    ushort4 b = *(const ushort4*)(p + 256 + t * 4);
    float ax = bf2f(a.x), ay = bf2f(a.y), az = bf2f(a.z), aw = bf2f(a.w);
    float bx = bf2f(b.x), by = bf2f(b.y), bz = bf2f(b.z), bw = bf2f(b.w);
    float v = ax * ax + ay * ay + az * az + aw * aw +
              bx * bx + by * by + bz * bz + bw * bw;
    for (int off = 32; off > 0; off >>= 1) v += __shfl_down(v, off);
    if (t == 0) outv[r] = v;
}

__global__ void bcomb_k(const float* __restrict__ b_enc,
                        const float* __restrict__ W_key,
                        const float* __restrict__ b_key,
                        float* __restrict__ b_comb) {
    int h = blockIdx.x * 256 + threadIdx.x;
    if (h >= H_) return;
    float acc = b_key[h];
    for (int m = 0; m < H_; ++m)
        acc = fmaf(b_enc[m], W_key[(size_t)m * H_ + h], acc);
    b_comb[h] = acc;
}

__global__ __launch_bounds__(128) void softmax_k(const float* __restrict__ topVal,
                                                 float* __restrict__ attn) {
    __shared__ float red[128];
    const int b = blockIdx.x, t = threadIdx.x;
    float v = (t < K_) ? -sqrtf(topVal[b * K_ + t]) : -FLT_MAX;
    red[t] = v; __syncthreads();
    for (int s = 64; s > 0; s >>= 1) {
        if (t < s) red[t] = fmaxf(red[t], red[t + s]);
        __syncthreads();
    }
    float m = red[0]; __syncthreads();
    float e = (t < K_) ? expf(v - m) : 0.f;
    red[t] = e; __syncthreads();
    for (int s = 64; s > 0; s >>= 1) {
        if (t < s) red[t] += red[t + s];
        __syncthreads();
    }
    float ssum = red[0];
    if (t < K_) attn[b * K_ + t] = e / ssum;
}

__global__ __launch_bounds__(128) void gather_diff_b(const float* __restrict__ XK,
                                                     const ushort* __restrict__ CK,
                                                     const int* __restrict__ topI,
                                                     ushort* __restrict__ diff,
                                                     int b0) {
    const int r = blockIdx.x;
    const int b = b0 + r / K_;
    const int idx = topI[b * K_ + (r % K_)];
    const int t = threadIdx.x;
    float4 xv = *(const float4*)(XK + (size_t)b * H_ + t * 4);
    ushort4 cv = *(const ushort4*)(CK + (size_t)idx * H_ + t * 4);
    ushort4 o;
    o.x = f2bf(xv.x - bf2f(cv.x));
    o.y = f2bf(xv.y - bf2f(cv.y));
    o.z = f2bf(xv.z - bf2f(cv.z));
    o.w = f2bf(xv.w - bf2f(cv.w));
    *(ushort4*)(diff + (size_t)r * H_ + t * 4) = o;
}

__global__ __launch_bounds__(256) void reduce_ctx(const float* __restrict__ attn,
                                                  const int* __restrict__ topI,
                                                  const int* __restrict__ labels,
                                                  const float* __restrict__ E,
                                                  const ushort* __restrict__ tout,
                                                  const float* __restrict__ xe,
                                                  float* __restrict__ out, int b0) {
    const int bl = blockIdx.x;
    const int b = b0 + bl;
    const int t = threadIdx.x;
    float a0 = 0.f, a1 = 0.f;
    for (int k = 0; k < K_; ++k) {
        float w = attn[b * K_ + k];
        int idx = topI[b * K_ + k];
        int lab = labels[idx];
        const float* el = E + (size_t)lab * H_;
        const ushort* tr = tout + (size_t)(bl * K_ + k) * H_;
        a0 = fmaf(w, el[t] + bf2f(tr[t]), a0);
        a1 = fmaf(w, el[t + 256] + bf2f(tr[t + 256]), a1);
    }
    out[(size_t)b * H_ + t]       = xe[(size_t)b * H_ + t] + a0;
    out[(size_t)b * H_ + t + 256] = xe[(size_t)b * H_ + t + 256] + a1;
}

// ---------------------------------------------------------------------------
extern "C" void kernel_launch(void* const* d_in, const int* in_sizes, int n_in,
                              void* d_out, int out_size, void* d_ws, size_t ws_size,
                              hipStream_t stream) {
    const float* x      = (const float*)d_in[0];
    const float* cx     = (const float*)d_in[1];
    const int*   labels = (const int*)d_in[2];
    const float* W_enc  = (const float*)d_in[3];
    const float* b_enc  = (const float*)d_in[4];
    const float* W_key  = (const float*)d_in[5];
    const float* b_key  = (const float*)d_in[6];
    // d_in[7]=W_val, d_in[8]=b_val dead (gather unused in reference)
    const float* E_label = (const float*)d_in[9];
    const float* W_t1   = (const float*)d_in[10];
    const float* b_t1   = (const float*)d_in[11];
    const float* W_t2   = (const float*)d_in[12];
    float* out = (float*)d_out;

    char* base = (char*)d_ws;
    size_t off = 0;
    auto take = [&](size_t n) -> char* {
        char* p = base + off;
        off = (off + n + 255) & ~(size_t)255;
        return p;
    };
    float*  Wc    = (float*)take((size_t)D_ * H_ * 4);
    float*  bc    = (float*)take((size_t)H_ * 4);
    ushort* WcT   = (ushort*)take((size_t)H_ * D_ * 2);
    ushort* Wt1T  = (ushort*)take((size_t)H_ * H_ * 2);
    ushort* Wt2T  = (ushort*)take((size_t)H_ * H_ * 2);
    float*  xe    = (float*)take((size_t)B_ * H_ * 4);
    float*  xk    = (float*)take((size_t)B_ * H_ * 4);
    ushort* xkb   = (ushort*)take((size_t)B_ * H_ * 2);
    float*  q2    = (float*)take((size_t)B_ * 4);
    ushort* ckb   = (ushort*)take((size_t)N_ * H_ * 2);
    float*  c2    = (float*)take((size_t)N_ * 4);
    float*  topV  = (float*)take((size_t)B_ * K_ * 4);
    int*    topI  = (int*)take((size_t)B_ * K_ * 4);
    float*  thr   = (float*)take((size_t)B_ * 4);
    float*  attn  = (float*)take((size_t)B_ * K_ * 4);
    int*    cnt   = (int*)take((size_t)B_ * 4);
    float*  candV = (float*)take((size_t)B_ * CAPC * 4);
    int*    candI = (int*)take((size_t)B_ * CAPC * 4);
    char*   big   = base + off;      // shared: cxb -> simBuf -> stage4 bufs
    size_t rem = (ws_size > off) ? (ws_size - off) : 0;

    ushort* cxb    = (ushort*)big;   // N*D*2 = 51.2 MB (dead after stage 2)
    float*  simBuf = (float*)big;    // B*Nc0*4

    long long nc = (long long)((rem / ((size_t)B_ * 4)) & ~(size_t)127);
    if (nc > 25600) nc = 25600;      // ~100 MB chunk: stays mostly in L3 for filter
    if (nc < SAMP) nc = SAMP;        // thr_select reads first SAMP cols of chunk 0
    int Nc0 = (int)nc;

    long long bcq = (long long)(rem / ((size_t)K_ * H_ * 2 * 2));
    if (bcq > B_) bcq = B_;
    if (bcq < 1) bcq = 1;
    int Bc = (int)bcq;

    // stage 0: combined candidate weights + transposed bf16 weights
    {
        dim3 g(H_ / 64, D_ / 64);
        gemm_nn<0><<<g, 256, 0, stream>>>(W_enc, W_key, nullptr, Wc, D_, H_, H_);
        bcomb_k<<<(H_ + 255) / 256, 256, 0, stream>>>(b_enc, W_key, b_key, bc);
        dim3 gt1((H_ + 31) / 32, (D_ + 31) / 32);
        transpose_f2b<<<gt1, 256, 0, stream>>>(Wc, WcT, D_, H_);
        dim3 gt2((H_ + 31) / 32, (H_ + 31) / 32);
        transpose_f2b<<<gt2, 256, 0, stream>>>(W_t1, Wt1T, H_, H_);
        transpose_f2b<<<gt2, 256, 0, stream>>>(W_t2, Wt2T, H_, H_);
    }
    // stage 1: query encodes (fp32, tiny) + bf16 conversions
    {
        dim3 gx(H_ / 64, B_ / 64);
        gemm_nn<0><<<gx, 256, 0, stream>>>(x, W_enc, b_enc, xe, B_, H_, D_);
        gemm_nn<0><<<gx, 256, 0, stream>>>(x, Wc, bc, xk, B_, H_, D_);
        conv_f2b<<<1024, 256, 0, stream>>>(xk, xkb, B_ * H_);
        conv_f2b<<<2048, 256, 0, stream>>>(cx, cxb, N_ * D_);
    }
    // stage 2: candidate keys via bf16 MFMA (bias, no relu); SWZ=2 keeps the
    // 4 H-tiles sharing an A-tile on one XCD (A streamed once, not 4x).
    {
        int mt = (N_ + 127) / 128;           // 782
        int mper = (mt + 7) / 8;             // 98
        gemm_nt<3, 2><<<8 * mper * 4, 256, 0, stream>>>(
            cxb, WcT, bc, ckb, N_, H_, D_, H_, H_, mper);
    }
    rowsq_b<<<N_, 64, 0, stream>>>(ckb, c2);
    rowsq_b<<<B_, 64, 0, stream>>>(xkb, q2);

    // stage 3: chunked sim GEMM (raw dot, SWZ=1: B-tile per XCD) ->
    //          (chunk 0: d2 threshold) -> LDS-staged d2 filter
    init_cnt<<<(B_ + 255) / 256, 256, 0, stream>>>(cnt);
    for (int j0 = 0; j0 < N_; j0 += Nc0) {
        int ncols = min(Nc0, N_ - j0);
        int NT = (ncols + 127) / 128;
        int nper = (NT + 7) / 8;
        gemm_nt<2, 1><<<64 * nper, 256, 0, stream>>>(
            xkb, ckb + (size_t)j0 * H_, nullptr, simBuf,
            B_, N_ - j0, H_, Nc0, ncols, nper);
        if (j0 == 0)
            thr_select<<<B_, 256, 0, stream>>>(simBuf, Nc0, q2, c2, thr);
        dim3 gf((ncols + FCOLS - 1) / FCOLS, B_);
        filter_sim<<<gf, 256, 0, stream>>>(simBuf, Nc0, ncols, j0, q2, c2 + j0,
                                           thr, candV, candI, cnt);
    }
    final_select<<<B_, 256, 0, stream>>>(candV, candI, cnt, topV, topI);
    softmax_k<<<B_, 128, 0, stream>>>(topV, attn);

    // stage 4: correction MLP (bf16 MFMA, SWZ=2) + weighted reduce
    ushort* diffB = (ushort*)big;
    ushort* hB = (ushort*)(big + (size_t)Bc * K_ * H_ * 2);
    for (int b0 = 0; b0 < B_; b0 += Bc) {
        int bcn = min(Bc, B_ - b0);
        int Mrows = bcn * K_;
        gather_diff_b<<<Mrows, 128, 0, stream>>>(xk, ckb, topI, diffB, b0);
        int mt4 = (Mrows + 127) / 128;
        int mper4 = (mt4 + 7) / 8;
        gemm_nt<1, 2><<<8 * mper4 * 4, 256, 0, stream>>>(
            diffB, Wt1T, b_t1, hB, Mrows, H_, H_, H_, H_, mper4);
        gemm_nt<0, 2><<<8 * mper4 * 4, 256, 0, stream>>>(
            hB, Wt2T, nullptr, diffB, Mrows, H_, H_, H_, H_, mper4);
        reduce_ctx<<<bcn, 256, 0, stream>>>(attn, topI, labels, E_label,
                                            diffB, xe, out, b0);
    }
}

// Round 7
// 1036.159 us; speedup vs baseline: 2.3506x; 1.0336x over previous
//
#include <hip/hip_runtime.h>
#include <cfloat>
#include <cmath>

#define B_ 1024
#define D_ 256
#define H_ 512
#define N_ 100000
#define K_ 96
#define C_ 10
#define SAMP 8192      // sample columns for threshold estimation
#define CAPC 4096      // per-row candidate capacity (expected ~1170 survivors)
#define RCAP 15        // per-row per-tile LDS staging slots (mean 1.25, P(>15)~4e-12)

typedef __attribute__((ext_vector_type(8))) short bf16x8;
typedef __attribute__((ext_vector_type(4))) float f32x4;

__device__ __forceinline__ float bf2f(ushort h) {
    union { unsigned u; float f; } v; v.u = ((unsigned)h) << 16; return v.f;
}
__device__ __forceinline__ ushort f2bf(float f) {
    union { float f; unsigned u; } v; v.f = f;
    unsigned u = v.u;
    unsigned r = (u + 0x7fffu + ((u >> 16) & 1u)) >> 16;
    return (ushort)r;
}
// monotone fp32 -> u32 (ascending)
__device__ __forceinline__ unsigned f2key(float f) {
    unsigned u = __float_as_uint(f);
    return (u & 0x80000000u) ? ~u : (u | 0x80000000u);
}
// d^2 from raw dot product -- single definition shared by thr_select and the
// fused GEMM epilogue so sample-column recompute is bitwise identical.
__device__ __forceinline__ float d2_of(float acc, float q2, float c2) {
    return fmaxf(fmaf(-2.f, acc, q2 + c2), 0.f);
}

#define GLDS(g, l)                                                            \
    __builtin_amdgcn_global_load_lds(                                         \
        (const __attribute__((address_space(1))) void*)(g),                   \
        (__attribute__((address_space(3))) void*)(l), 16, 0, 0)

// ---------------------------------------------------------------------------
// fp32 tiled GEMM (kept for tiny fp32 GEMMs: Wc, xe, xk)
// ---------------------------------------------------------------------------
template <int RELU>
__global__ __launch_bounds__(256) void gemm_nn(const float* __restrict__ A,
                                               const float* __restrict__ Bm,
                                               const float* __restrict__ bias,
                                               float* __restrict__ Cm,
                                               int M, int N, int Kd) {
    __shared__ float sA[16][68];
    __shared__ float sB[16][64];
    const int t  = threadIdx.x;
    const int tx = t & 15, ty = t >> 4;
    const int m0 = blockIdx.y * 64;
    const int n0 = blockIdx.x * 64;
    const int lr = t >> 2;
    const int lk = (t & 3) << 2;
    const int bk = t >> 4;
    const int bn = (t & 15) << 2;

    float acc[4][4] = {};
    for (int k0 = 0; k0 < Kd; k0 += 16) {
        float4 av = make_float4(0.f, 0.f, 0.f, 0.f);
        if (m0 + lr < M)
            av = *(const float4*)(A + (size_t)(m0 + lr) * Kd + k0 + lk);
        sA[lk + 0][lr] = av.x; sA[lk + 1][lr] = av.y;
        sA[lk + 2][lr] = av.z; sA[lk + 3][lr] = av.w;
        float4 bv = *(const float4*)(Bm + (size_t)(k0 + bk) * N + n0 + bn);
        *(float4*)&sB[bk][bn] = bv;
        __syncthreads();
#pragma unroll
        for (int kk = 0; kk < 16; ++kk) {
            float4 a4 = *(const float4*)&sA[kk][ty << 2];
            float4 b4 = *(const float4*)&sB[kk][tx << 2];
            float ar[4] = {a4.x, a4.y, a4.z, a4.w};
            float br[4] = {b4.x, b4.y, b4.z, b4.w};
#pragma unroll
            for (int i = 0; i < 4; ++i)
#pragma unroll
                for (int j = 0; j < 4; ++j)
                    acc[i][j] = fmaf(ar[i], br[j], acc[i][j]);
        }
        __syncthreads();
    }
#pragma unroll
    for (int i = 0; i < 4; ++i) {
        int row = m0 + (ty << 2) + i;
        if (row < M) {
            int col = n0 + (tx << 2);
            float b0 = 0.f, b1 = 0.f, b2 = 0.f, b3 = 0.f;
            if (bias) { b0 = bias[col]; b1 = bias[col + 1]; b2 = bias[col + 2]; b3 = bias[col + 3]; }
            float4 o;
            o.x = acc[i][0] + b0; o.y = acc[i][1] + b1;
            o.z = acc[i][2] + b2; o.w = acc[i][3] + b3;
            if (RELU) {
                o.x = fmaxf(o.x, 0.f); o.y = fmaxf(o.y, 0.f);
                o.z = fmaxf(o.z, 0.f); o.w = fmaxf(o.w, 0.f);
            }
            *(float4*)(Cm + (size_t)row * N + col) = o;
        }
    }
}

// ---------------------------------------------------------------------------
// bf16 MFMA NT GEMM: C = epilogue(A[M,K] @ B[N,K]^T)
// 128x128 tile, BK=32, 4 waves, each 4x4 tiles of 16x16x32 MFMA.
// SWZ=0: 2-D grid. SWZ=1: 1-D grid, 8 M-tiles sharing a B-tile on one XCD
// (needs M==1024). SWZ=2: 1-D grid, 4 N-tiles sharing an A-tile on one XCD
// (needs Nlim==512).
// MODE 0: out bf16     MODE 1: +bias, relu, out bf16
// MODE 2: raw dot product -> fp32 Cout (sample sim)
// MODE 3: +bias (no relu), out bf16
// MODE 5: fused sim filter: d2<=thr[row] survivors staged in reused LDS,
//         per-row batch append to candV/candI (no C written at all)
// ---------------------------------------------------------------------------
template <int MODE, int SWZ>
__global__ __launch_bounds__(256) void gemm_nt(const ushort* __restrict__ A,
                                               const ushort* __restrict__ Bv,
                                               const float* __restrict__ bias,
                                               const float* __restrict__ q2v,
                                               const float* __restrict__ c2v,
                                               const float* __restrict__ thrv,
                                               float* __restrict__ candV,
                                               int* __restrict__ candI,
                                               int* __restrict__ cnt,
                                               void* __restrict__ Cout,
                                               int M, int Nlim, int K,
                                               int ldc, int nvalid, int per) {
    int m0, n0;
    if (SWZ == 0) {
        m0 = blockIdx.y * 128; n0 = blockIdx.x * 128;
    } else if (SWZ == 1) {
        int bid = blockIdx.x;
        int xcd = bid & 7, slot = bid >> 3;
        m0 = (slot & 7) * 128;
        n0 = (xcd * per + (slot >> 3)) * 128;
        if (n0 >= nvalid || m0 >= M) return;
    } else {
        int bid = blockIdx.x;
        int xcd = bid & 7, slot = bid >> 3;
        n0 = (slot & 3) * 128;
        m0 = (xcd * per + (slot >> 2)) * 128;
        if (m0 >= M) return;
    }

    __shared__ __align__(16) char smem[16896];
    ushort* sA = (ushort*)smem;            // 8192 B
    ushort* sB = (ushort*)(smem + 8192);   // 8192 B
    const int t = threadIdx.x;
    const int lane = t & 63, w = t >> 6;
    const int wm = w & 1, wn = w >> 1;

    f32x4 acc[4][4];
#pragma unroll
    for (int i = 0; i < 4; ++i)
#pragma unroll
        for (int j = 0; j < 4; ++j)
            acc[i][j] = (f32x4){0.f, 0.f, 0.f, 0.f};

    const int la = lane & 15, lk = lane >> 4;
    const int aoff = (wm * 64 + la) * 64 + lk * 16;
    const int boff = (wn * 64 + la) * 64 + lk * 16;
    const int r_ = t >> 2, cc_ = (t & 3);

    for (int k0 = 0; k0 < K; k0 += 32) {
#pragma unroll
        for (int q = 0; q < 2; ++q) {
            int r = r_ + q * 64;
            int ar = m0 + r; ar = (ar < M) ? ar : (M - 1);
            GLDS(A + (size_t)ar * K + k0 + cc_ * 8, (char*)sA + (q * 256 + t) * 16);
            int br = n0 + r; br = (br < Nlim) ? br : (Nlim - 1);
            GLDS(Bv + (size_t)br * K + k0 + cc_ * 8, (char*)sB + (q * 256 + t) * 16);
        }
        __syncthreads();
        bf16x8 af[4], bfr[4];
#pragma unroll
        for (int i = 0; i < 4; ++i)
            af[i] = *(const bf16x8*)((const char*)sA + aoff + i * 1024);
#pragma unroll
        for (int j = 0; j < 4; ++j)
            bfr[j] = *(const bf16x8*)((const char*)sB + boff + j * 1024);
#pragma unroll
        for (int i = 0; i < 4; ++i)
#pragma unroll
            for (int j = 0; j < 4; ++j)
                acc[i][j] = __builtin_amdgcn_mfma_f32_16x16x32_bf16(
                    af[i], bfr[j], acc[i][j], 0, 0, 0);
        __syncthreads();
    }

    const int rl = (lane >> 4) * 4, cl = lane & 15;

    if (MODE == 5) {
        // sA/sB are dead after the final barrier -- reuse as staging.
        float* stV = (float*)smem;               // [128][RCAP] = 7680 B
        int*   stI = (int*)(smem + 7680);        // [128][RCAP] = 7680 B
        int*   stC = (int*)(smem + 16384);       // [128]       =  512 B
        for (int r = t; r < 128; r += 256) stC[r] = 0;
        __syncthreads();
#pragma unroll
        for (int i = 0; i < 4; ++i) {
#pragma unroll
            for (int v = 0; v < 4; ++v) {
                int rloc = wm * 64 + i * 16 + rl + v;
                int gr = m0 + rloc;
                float q2b = q2v[gr];
                float th = thrv[gr];
#pragma unroll
                for (int j = 0; j < 4; ++j) {
                    int gc = n0 + wn * 64 + j * 16 + cl;
                    if (gc < nvalid) {
                        float d2 = d2_of(acc[i][j][v], q2b, c2v[gc]);
                        if (d2 <= th) {
                            int p = atomicAdd(&stC[rloc], 1);
                            if (p < RCAP) {
                                stV[rloc * RCAP + p] = d2;
                                stI[rloc * RCAP + p] = gc;
                            }
                        }
                    }
                }
            }
        }
        __syncthreads();
        for (int r = t; r < 128; r += 256) {
            int n = stC[r]; if (n > RCAP) n = RCAP;
            if (n > 0) {
                int gr = m0 + r;
                int gb = atomicAdd(&cnt[gr], n);
                for (int q = 0; q < n; ++q) {
                    int pos = gb + q;
                    if (pos < CAPC) {
                        candV[(size_t)gr * CAPC + pos] = stV[r * RCAP + q];
                        candI[(size_t)gr * CAPC + pos] = stI[r * RCAP + q];
                    }
                }
            }
        }
        return;
    }

#pragma unroll
    for (int i = 0; i < 4; ++i) {
#pragma unroll
        for (int j = 0; j < 4; ++j) {
            int gc = n0 + wn * 64 + j * 16 + cl;
#pragma unroll
            for (int v = 0; v < 4; ++v) {
                int gr = m0 + wm * 64 + i * 16 + rl + v;
                if (gr < M && gc < nvalid) {
                    float val = acc[i][j][v];
                    if (MODE == 2) {
                        ((float*)Cout)[(size_t)gr * ldc + gc] = val;
                    } else {
                        if (MODE == 1 || MODE == 3) val += bias[gc];
                        if (MODE == 1) val = fmaxf(val, 0.f);
                        ((ushort*)Cout)[(size_t)gr * ldc + gc] = f2bf(val);
                    }
                }
            }
        }
    }
}

// ---------------------------------------------------------------------------
// per-row radix-select of the 96th-SMALLEST d^2 over the first SAMP columns.
// S holds raw dot products; keys inverted so largest key == smallest d^2.
// ---------------------------------------------------------------------------
__global__ __launch_bounds__(256) void thr_select(const float* __restrict__ S,
                                                  int ld,
                                                  const float* __restrict__ q2v,
                                                  const float* __restrict__ c2v,
                                                  float* __restrict__ thrArr) {
    __shared__ unsigned keys[SAMP];
    __shared__ int hist[256];
    __shared__ int sel[2];
    const int b = blockIdx.x, t = threadIdx.x;
    const float q2b = q2v[b];
    for (int i = t; i < SAMP; i += 256)
        keys[i] = ~f2key(d2_of(S[(size_t)b * ld + i], q2b, c2v[i]));
    __syncthreads();
    unsigned prefix = 0, mask = 0;
    int rank = K_;
    for (int shift = 24; shift >= 0; shift -= 8) {
        hist[t & 255] = 0;
        __syncthreads();
        for (int i = t; i < SAMP; i += 256) {
            unsigned k = keys[i];
            if ((k & mask) == prefix) atomicAdd(&hist[(k >> shift) & 255], 1);
        }
        __syncthreads();
        if (t == 0) {
            int r = rank, d = 255;
            for (; d > 0; --d) { int c = hist[d]; if (r - c <= 0) break; r -= c; }
            sel[0] = d; sel[1] = (r < 1) ? 1 : r;
        }
        __syncthreads();
        prefix |= ((unsigned)sel[0]) << shift;
        rank = sel[1];
        mask |= (0xFFu << shift);
        __syncthreads();
    }
    if (t == 0) {
        unsigned key = ~prefix;
        thrArr[b] = __uint_as_float(key & 0x7FFFFFFFu);
    }
}

// ---------------------------------------------------------------------------
// per-row exact 96-smallest-d2 from candidate buffer via radix select
// (inverted keys) + compaction. topV receives d2.
// ---------------------------------------------------------------------------
__global__ __launch_bounds__(256) void final_select(const float* __restrict__ candV,
                                                    const int* __restrict__ candI,
                                                    const int* __restrict__ cnt,
                                                    float* __restrict__ topV,
                                                    int* __restrict__ topI) {
    __shared__ unsigned keys[CAPC];
    __shared__ int hist[256];
    __shared__ int sel[2];
    __shared__ int poscnt, eqcnt;
    const int b = blockIdx.x, t = threadIdx.x;
    int n = cnt[b]; if (n > CAPC) n = CAPC;
    for (int i = t; i < n; i += 256)
        keys[i] = ~f2key(candV[(size_t)b * CAPC + i]);
    __syncthreads();
    unsigned prefix = 0, mask = 0;
    int rank = K_;
    for (int shift = 24; shift >= 0; shift -= 8) {
        hist[t & 255] = 0;
        __syncthreads();
        for (int i = t; i < n; i += 256) {
            unsigned k = keys[i];
            if ((k & mask) == prefix) atomicAdd(&hist[(k >> shift) & 255], 1);
        }
        __syncthreads();
        if (t == 0) {
            int r = rank, d = 255;
            for (; d > 0; --d) { int c = hist[d]; if (r - c <= 0) break; r -= c; }
            sel[0] = d; sel[1] = (r < 1) ? 1 : r;
        }
        __syncthreads();
        prefix |= ((unsigned)sel[0]) << shift;
        rank = sel[1];
        mask |= (0xFFu << shift);
        __syncthreads();
    }
    unsigned kth = prefix;
    if (t == 0) { poscnt = 0; eqcnt = 0; }
    __syncthreads();
    for (int i = t; i < n; i += 256) {
        if (keys[i] > kth) {
            int p = atomicAdd(&poscnt, 1);
            topV[b * K_ + p] = candV[(size_t)b * CAPC + i];
            topI[b * K_ + p] = candI[(size_t)b * CAPC + i];
        }
    }
    __syncthreads();
    int base = poscnt;
    for (int i = t; i < n; i += 256) {
        if (keys[i] == kth) {
            int p = atomicAdd(&eqcnt, 1);
            if (base + p < K_) {
                topV[b * K_ + base + p] = candV[(size_t)b * CAPC + i];
                topI[b * K_ + base + p] = candI[(size_t)b * CAPC + i];
            }
        }
    }
}

__global__ void init_cnt(int* cnt) {
    int i = blockIdx.x * 256 + threadIdx.x;
    if (i < B_) cnt[i] = 0;
}

// ---------------------------------------------------------------------------
__global__ void conv_f2b(const float* __restrict__ in, ushort* __restrict__ out, int n) {
    int i = (blockIdx.x * 256 + threadIdx.x) * 4;
    int stride = gridDim.x * 256 * 4;
    for (; i < n; i += stride) {
        float4 v = *(const float4*)(in + i);
        ushort4 o;
        o.x = f2bf(v.x); o.y = f2bf(v.y); o.z = f2bf(v.z); o.w = f2bf(v.w);
        *(ushort4*)(out + i) = o;
    }
}

__global__ __launch_bounds__(256) void transpose_f2b(const float* __restrict__ in,
                                                     ushort* __restrict__ out,
                                                     int R, int Cn) {
    __shared__ float tile[32][33];
    int bx = blockIdx.x * 32, by = blockIdx.y * 32;
    int tx = threadIdx.x & 31, ty = threadIdx.x >> 5;
    int x = bx + tx;
#pragma unroll
    for (int dy = 0; dy < 32; dy += 8) {
        int y = by + ty + dy;
        if (x < Cn && y < R) tile[ty + dy][tx] = in[(size_t)y * Cn + x];
    }
    __syncthreads();
    int ox = by + tx;
#pragma unroll
    for (int dy = 0; dy < 32; dy += 8) {
        int oy = bx + ty + dy;
        if (ox < R && oy < Cn) out[(size_t)oy * R + ox] = f2bf(tile[tx][ty + dy]);
    }
}

__global__ __launch_bounds__(64) void rowsq_b(const ushort* __restrict__ X,
                                              float* __restrict__ outv) {
    const int r = blockIdx.x, t = threadIdx.x;
    const ushort* p = X + (size_t)r * H_;
    ushort4 a = *(const ushort4*)(p + t * 4);
    ushort4 b = *(const ushort4*)(p + 256 + t * 4);
    float ax = bf2f(a.x), ay = bf2f(a.y), az = bf2f(a.z), aw = bf2f(a.w);
    float bx = bf2f(b.x), by = bf2f(b.y), bz = bf2f(b.z), bw = bf2f(b.w);
    float v = ax * ax + ay * ay + az * az + aw * aw +
              bx * bx + by * by + bz * bz + bw * bw;
    for (int off = 32; off > 0; off >>= 1) v += __shfl_down(v, off);
    if (t == 0) outv[r] = v;
}

__global__ void bcomb_k(const float* __restrict__ b_enc,
                        const float* __restrict__ W_key,
                        const float* __restrict__ b_key,
                        float* __restrict__ b_comb) {
    int h = blockIdx.x * 256 + threadIdx.x;
    if (h >= H_) return;
    float acc = b_key[h];
    for (int m = 0; m < H_; ++m)
        acc = fmaf(b_enc[m], W_key[(size_t)m * H_ + h], acc);
    b_comb[h] = acc;
}

__global__ __launch_bounds__(128) void softmax_k(const float* __restrict__ topVal,
                                                 float* __restrict__ attn) {
    __shared__ float red[128];
    const int b = blockIdx.x, t = threadIdx.x;
    float v = (t < K_) ? -sqrtf(topVal[b * K_ + t]) : -FLT_MAX;
    red[t] = v; __syncthreads();
    for (int s = 64; s > 0; s >>= 1) {
        if (t < s) red[t] = fmaxf(red[t], red[t + s]);
        __syncthreads();
    }
    float m = red[0]; __syncthreads();
    float e = (t < K_) ? expf(v - m) : 0.f;
    red[t] = e; __syncthreads();
    for (int s = 64; s > 0; s >>= 1) {
        if (t < s) red[t] += red[t + s];
        __syncthreads();
    }
    float ssum = red[0];
    if (t < K_) attn[b * K_ + t] = e / ssum;
}

__global__ __launch_bounds__(128) void gather_diff_b(const float* __restrict__ XK,
                                                     const ushort* __restrict__ CK,
                                                     const int* __restrict__ topI,
                                                     ushort* __restrict__ diff,
                                                     int b0) {
    const int r = blockIdx.x;
    const int b = b0 + r / K_;
    const int idx = topI[b * K_ + (r % K_)];
    const int t = threadIdx.x;
    float4 xv = *(const float4*)(XK + (size_t)b * H_ + t * 4);
    ushort4 cv = *(const ushort4*)(CK + (size_t)idx * H_ + t * 4);
    ushort4 o;
    o.x = f2bf(xv.x - bf2f(cv.x));
    o.y = f2bf(xv.y - bf2f(cv.y));
    o.z = f2bf(xv.z - bf2f(cv.z));
    o.w = f2bf(xv.w - bf2f(cv.w));
    *(ushort4*)(diff + (size_t)r * H_ + t * 4) = o;
}

__global__ __launch_bounds__(256) void reduce_ctx(const float* __restrict__ attn,
                                                  const int* __restrict__ topI,
                                                  const int* __restrict__ labels,
                                                  const float* __restrict__ E,
                                                  const ushort* __restrict__ tout,
                                                  const float* __restrict__ xe,
                                                  float* __restrict__ out, int b0) {
    const int bl = blockIdx.x;
    const int b = b0 + bl;
    const int t = threadIdx.x;
    float a0 = 0.f, a1 = 0.f;
    for (int k = 0; k < K_; ++k) {
        float w = attn[b * K_ + k];
        int idx = topI[b * K_ + k];
        int lab = labels[idx];
        const float* el = E + (size_t)lab * H_;
        const ushort* tr = tout + (size_t)(bl * K_ + k) * H_;
        a0 = fmaf(w, el[t] + bf2f(tr[t]), a0);
        a1 = fmaf(w, el[t + 256] + bf2f(tr[t + 256]), a1);
    }
    out[(size_t)b * H_ + t]       = xe[(size_t)b * H_ + t] + a0;
    out[(size_t)b * H_ + t + 256] = xe[(size_t)b * H_ + t + 256] + a1;
}

// ---------------------------------------------------------------------------
extern "C" void kernel_launch(void* const* d_in, const int* in_sizes, int n_in,
                              void* d_out, int out_size, void* d_ws, size_t ws_size,
                              hipStream_t stream) {
    const float* x      = (const float*)d_in[0];
    const float* cx     = (const float*)d_in[1];
    const int*   labels = (const int*)d_in[2];
    const float* W_enc  = (const float*)d_in[3];
    const float* b_enc  = (const float*)d_in[4];
    const float* W_key  = (const float*)d_in[5];
    const float* b_key  = (const float*)d_in[6];
    // d_in[7]=W_val, d_in[8]=b_val dead (gather unused in reference)
    const float* E_label = (const float*)d_in[9];
    const float* W_t1   = (const float*)d_in[10];
    const float* b_t1   = (const float*)d_in[11];
    const float* W_t2   = (const float*)d_in[12];
    float* out = (float*)d_out;

    char* base = (char*)d_ws;
    size_t off = 0;
    auto take = [&](size_t n) -> char* {
        char* p = base + off;
        off = (off + n + 255) & ~(size_t)255;
        return p;
    };
    float*  Wc    = (float*)take((size_t)D_ * H_ * 4);
    float*  bc    = (float*)take((size_t)H_ * 4);
    ushort* WcT   = (ushort*)take((size_t)H_ * D_ * 2);
    ushort* Wt1T  = (ushort*)take((size_t)H_ * H_ * 2);
    ushort* Wt2T  = (ushort*)take((size_t)H_ * H_ * 2);
    float*  xe    = (float*)take((size_t)B_ * H_ * 4);
    float*  xk    = (float*)take((size_t)B_ * H_ * 4);
    ushort* xkb   = (ushort*)take((size_t)B_ * H_ * 2);
    float*  q2    = (float*)take((size_t)B_ * 4);
    ushort* ckb   = (ushort*)take((size_t)N_ * H_ * 2);
    float*  c2    = (float*)take((size_t)N_ * 4);
    float*  topV  = (float*)take((size_t)B_ * K_ * 4);
    int*    topI  = (int*)take((size_t)B_ * K_ * 4);
    float*  thr   = (float*)take((size_t)B_ * 4);
    float*  attn  = (float*)take((size_t)B_ * K_ * 4);
    int*    cnt   = (int*)take((size_t)B_ * 4);
    float*  candV = (float*)take((size_t)B_ * CAPC * 4);
    int*    candI = (int*)take((size_t)B_ * CAPC * 4);
    char*   big   = base + off;      // shared: cxb -> simSmall -> stage4 bufs
    size_t rem = (ws_size > off) ? (ws_size - off) : 0;

    ushort* cxb      = (ushort*)big;  // N*D*2 = 51.2 MB (dead after stage 2)
    float*  simSmall = (float*)big;   // B*SAMP*4 = 33.5 MB (dead after thr_select)

    long long bcq = (long long)(rem / ((size_t)K_ * H_ * 2 * 2));
    if (bcq > B_) bcq = B_;
    if (bcq < 1) bcq = 1;
    int Bc = (int)bcq;

    // stage 0: combined candidate weights + transposed bf16 weights
    {
        dim3 g(H_ / 64, D_ / 64);
        gemm_nn<0><<<g, 256, 0, stream>>>(W_enc, W_key, nullptr, Wc, D_, H_, H_);
        bcomb_k<<<(H_ + 255) / 256, 256, 0, stream>>>(b_enc, W_key, b_key, bc);
        dim3 gt1((H_ + 31) / 32, (D_ + 31) / 32);
        transpose_f2b<<<gt1, 256, 0, stream>>>(Wc, WcT, D_, H_);
        dim3 gt2((H_ + 31) / 32, (H_ + 31) / 32);
        transpose_f2b<<<gt2, 256, 0, stream>>>(W_t1, Wt1T, H_, H_);
        transpose_f2b<<<gt2, 256, 0, stream>>>(W_t2, Wt2T, H_, H_);
    }
    // stage 1: query encodes (fp32, tiny) + bf16 conversions
    {
        dim3 gx(H_ / 64, B_ / 64);
        gemm_nn<0><<<gx, 256, 0, stream>>>(x, W_enc, b_enc, xe, B_, H_, D_);
        gemm_nn<0><<<gx, 256, 0, stream>>>(x, Wc, bc, xk, B_, H_, D_);
        conv_f2b<<<1024, 256, 0, stream>>>(xk, xkb, B_ * H_);
        conv_f2b<<<2048, 256, 0, stream>>>(cx, cxb, N_ * D_);
    }
    // stage 2: candidate keys via bf16 MFMA (bias, no relu), SWZ=2
    {
        int mt = (N_ + 127) / 128;           // 782
        int mper = (mt + 7) / 8;             // 98
        gemm_nt<3, 2><<<8 * mper * 4, 256, 0, stream>>>(
            cxb, WcT, bc, nullptr, nullptr, nullptr, nullptr, nullptr, nullptr,
            ckb, N_, H_, D_, H_, H_, mper);
    }
    rowsq_b<<<N_, 64, 0, stream>>>(ckb, c2);
    rowsq_b<<<B_, 64, 0, stream>>>(xkb, q2);

    // stage 3a: sample sim GEMM (first SAMP cols, raw dot) -> d2 thresholds
    {
        int nper = (SAMP / 128 + 7) / 8;     // 8
        gemm_nt<2, 1><<<64 * nper, 256, 0, stream>>>(
            xkb, ckb, nullptr, nullptr, nullptr, nullptr, nullptr, nullptr,
            nullptr, simSmall, B_, N_, H_, SAMP, SAMP, nper);
        thr_select<<<B_, 256, 0, stream>>>(simSmall, SAMP, q2, c2, thr);
    }
    // stage 3b: fused sim GEMM + in-epilogue threshold filter over all N
    init_cnt<<<(B_ + 255) / 256, 256, 0, stream>>>(cnt);
    {
        int NT = (N_ + 127) / 128;           // 782
        int nper = (NT + 7) / 8;             // 98
        gemm_nt<5, 1><<<64 * nper, 256, 0, stream>>>(
            xkb, ckb, nullptr, q2, c2, thr, candV, candI, cnt,
            nullptr, B_, N_, H_, 0, N_, nper);
    }
    final_select<<<B_, 256, 0, stream>>>(candV, candI, cnt, topV, topI);
    softmax_k<<<B_, 128, 0, stream>>>(topV, attn);

    // stage 4: correction MLP (bf16 MFMA, SWZ=2) + weighted reduce
    ushort* diffB = (ushort*)big;
    ushort* hB = (ushort*)(big + (size_t)Bc * K_ * H_ * 2);
    for (int b0 = 0; b0 < B_; b0 += Bc) {
        int bcn = min(Bc, B_ - b0);
        int Mrows = bcn * K_;
        gather_diff_b<<<Mrows, 128, 0, stream>>>(xk, ckb, topI, diffB, b0);
        int mt4 = (Mrows + 127) / 128;
        int mper4 = (mt4 + 7) / 8;
        gemm_nt<1, 2><<<8 * mper4 * 4, 256, 0, stream>>>(
            diffB, Wt1T, b_t1, nullptr, nullptr, nullptr, nullptr, nullptr,
            nullptr, hB, Mrows, H_, H_, H_, H_, mper4);
        gemm_nt<0, 2><<<8 * mper4 * 4, 256, 0, stream>>>(
            hB, Wt2T, nullptr, nullptr, nullptr, nullptr, nullptr, nullptr,
            nullptr, diffB, Mrows, H_, H_, H_, H_, mper4);
        reduce_ctx<<<bcn, 256, 0, stream>>>(attn, topI, labels, E_label,
                                            diffB, xe, out, b0);
    }
}

// Round 8
// 970.153 us; speedup vs baseline: 2.5105x; 1.0680x over previous
//
#include <hip/hip_runtime.h>
#include <cfloat>
#include <cmath>

#define B_ 1024
#define D_ 256
#define H_ 512
#define N_ 100000
#define K_ 96
#define C_ 10
#define SAMP 8192      // sample columns for threshold estimation
#define CAPC 4096      // per-row candidate capacity (expected ~1170 survivors)
#define RCAP 15        // per-row per-tile LDS staging slots (mean 1.25, P(>15)~4e-12)

typedef __attribute__((ext_vector_type(8))) short bf16x8;
typedef __attribute__((ext_vector_type(4))) float f32x4;

__device__ __forceinline__ float bf2f(ushort h) {
    union { unsigned u; float f; } v; v.u = ((unsigned)h) << 16; return v.f;
}
__device__ __forceinline__ ushort f2bf(float f) {
    union { float f; unsigned u; } v; v.f = f;
    unsigned u = v.u;
    unsigned r = (u + 0x7fffu + ((u >> 16) & 1u)) >> 16;
    return (ushort)r;
}
// monotone fp32 -> u32 (ascending)
__device__ __forceinline__ unsigned f2key(float f) {
    unsigned u = __float_as_uint(f);
    return (u & 0x80000000u) ? ~u : (u | 0x80000000u);
}
// d^2 from raw dot product -- single definition shared by thr_select and the
// fused GEMM epilogue so sample-column recompute is bitwise identical.
__device__ __forceinline__ float d2_of(float acc, float q2, float c2) {
    return fmaxf(fmaf(-2.f, acc, q2 + c2), 0.f);
}

#define GLDS(g, l)                                                            \
    __builtin_amdgcn_global_load_lds(                                         \
        (const __attribute__((address_space(1))) void*)(g),                   \
        (__attribute__((address_space(3))) void*)(l), 16, 0, 0)

// ---------------------------------------------------------------------------
// fp32 tiled GEMM (kept for tiny fp32 GEMMs: Wc, xe, xk)
// ---------------------------------------------------------------------------
template <int RELU>
__global__ __launch_bounds__(256) void gemm_nn(const float* __restrict__ A,
                                               const float* __restrict__ Bm,
                                               const float* __restrict__ bias,
                                               float* __restrict__ Cm,
                                               int M, int N, int Kd) {
    __shared__ float sA[16][68];
    __shared__ float sB[16][64];
    const int t  = threadIdx.x;
    const int tx = t & 15, ty = t >> 4;
    const int m0 = blockIdx.y * 64;
    const int n0 = blockIdx.x * 64;
    const int lr = t >> 2;
    const int lk = (t & 3) << 2;
    const int bk = t >> 4;
    const int bn = (t & 15) << 2;

    float acc[4][4] = {};
    for (int k0 = 0; k0 < Kd; k0 += 16) {
        float4 av = make_float4(0.f, 0.f, 0.f, 0.f);
        if (m0 + lr < M)
            av = *(const float4*)(A + (size_t)(m0 + lr) * Kd + k0 + lk);
        sA[lk + 0][lr] = av.x; sA[lk + 1][lr] = av.y;
        sA[lk + 2][lr] = av.z; sA[lk + 3][lr] = av.w;
        float4 bv = *(const float4*)(Bm + (size_t)(k0 + bk) * N + n0 + bn);
        *(float4*)&sB[bk][bn] = bv;
        __syncthreads();
#pragma unroll
        for (int kk = 0; kk < 16; ++kk) {
            float4 a4 = *(const float4*)&sA[kk][ty << 2];
            float4 b4 = *(const float4*)&sB[kk][tx << 2];
            float ar[4] = {a4.x, a4.y, a4.z, a4.w};
            float br[4] = {b4.x, b4.y, b4.z, b4.w};
#pragma unroll
            for (int i = 0; i < 4; ++i)
#pragma unroll
                for (int j = 0; j < 4; ++j)
                    acc[i][j] = fmaf(ar[i], br[j], acc[i][j]);
        }
        __syncthreads();
    }
#pragma unroll
    for (int i = 0; i < 4; ++i) {
        int row = m0 + (ty << 2) + i;
        if (row < M) {
            int col = n0 + (tx << 2);
            float b0 = 0.f, b1 = 0.f, b2 = 0.f, b3 = 0.f;
            if (bias) { b0 = bias[col]; b1 = bias[col + 1]; b2 = bias[col + 2]; b3 = bias[col + 3]; }
            float4 o;
            o.x = acc[i][0] + b0; o.y = acc[i][1] + b1;
            o.z = acc[i][2] + b2; o.w = acc[i][3] + b3;
            if (RELU) {
                o.x = fmaxf(o.x, 0.f); o.y = fmaxf(o.y, 0.f);
                o.z = fmaxf(o.z, 0.f); o.w = fmaxf(o.w, 0.f);
            }
            *(float4*)(Cm + (size_t)row * N + col) = o;
        }
    }
}

// ---------------------------------------------------------------------------
// bf16 MFMA NT GEMM: C = epilogue(A[M,K] @ B[N,K]^T)
// 128x128 tile, BK=32, 4 waves, each 4x4 tiles of 16x16x32 MFMA.
// SWZ=0: 2-D grid. SWZ=1: 1-D grid, 8 M-tiles sharing a B-tile on one XCD
// (needs M==1024). SWZ=2: 1-D grid, 4 N-tiles sharing an A-tile on one XCD
// (needs Nlim==512).
// MODE 0: out bf16     MODE 1: +bias, relu, out bf16
// MODE 2: raw dot product -> fp32 Cout
// MODE 3: +bias (no relu), out bf16
// MODE 5: fused sim filter: d2<=thr[row] survivors staged in reused LDS,
//         per-row batch append to candV/candI (no C written at all)
// ---------------------------------------------------------------------------
template <int MODE, int SWZ>
__global__ __launch_bounds__(256) void gemm_nt(const ushort* __restrict__ A,
                                               const ushort* __restrict__ Bv,
                                               const float* __restrict__ bias,
                                               const float* __restrict__ q2v,
                                               const float* __restrict__ c2v,
                                               const float* __restrict__ thrv,
                                               float* __restrict__ candV,
                                               int* __restrict__ candI,
                                               int* __restrict__ cnt,
                                               void* __restrict__ Cout,
                                               int M, int Nlim, int K,
                                               int ldc, int nvalid, int per) {
    int m0, n0;
    if (SWZ == 0) {
        m0 = blockIdx.y * 128; n0 = blockIdx.x * 128;
    } else if (SWZ == 1) {
        int bid = blockIdx.x;
        int xcd = bid & 7, slot = bid >> 3;
        m0 = (slot & 7) * 128;
        n0 = (xcd * per + (slot >> 3)) * 128;
        if (n0 >= nvalid || m0 >= M) return;
    } else {
        int bid = blockIdx.x;
        int xcd = bid & 7, slot = bid >> 3;
        n0 = (slot & 3) * 128;
        m0 = (xcd * per + (slot >> 2)) * 128;
        if (m0 >= M) return;
    }

    __shared__ __align__(16) char smem[16896];
    ushort* sA = (ushort*)smem;            // 8192 B
    ushort* sB = (ushort*)(smem + 8192);   // 8192 B
    const int t = threadIdx.x;
    const int lane = t & 63, w = t >> 6;
    const int wm = w & 1, wn = w >> 1;

    f32x4 acc[4][4];
#pragma unroll
    for (int i = 0; i < 4; ++i)
#pragma unroll
        for (int j = 0; j < 4; ++j)
            acc[i][j] = (f32x4){0.f, 0.f, 0.f, 0.f};

    const int la = lane & 15, lk = lane >> 4;
    const int aoff = (wm * 64 + la) * 64 + lk * 16;
    const int boff = (wn * 64 + la) * 64 + lk * 16;
    const int r_ = t >> 2, cc_ = (t & 3);

    for (int k0 = 0; k0 < K; k0 += 32) {
#pragma unroll
        for (int q = 0; q < 2; ++q) {
            int r = r_ + q * 64;
            int ar = m0 + r; ar = (ar < M) ? ar : (M - 1);
            GLDS(A + (size_t)ar * K + k0 + cc_ * 8, (char*)sA + (q * 256 + t) * 16);
            int br = n0 + r; br = (br < Nlim) ? br : (Nlim - 1);
            GLDS(Bv + (size_t)br * K + k0 + cc_ * 8, (char*)sB + (q * 256 + t) * 16);
        }
        __syncthreads();
        bf16x8 af[4], bfr[4];
#pragma unroll
        for (int i = 0; i < 4; ++i)
            af[i] = *(const bf16x8*)((const char*)sA + aoff + i * 1024);
#pragma unroll
        for (int j = 0; j < 4; ++j)
            bfr[j] = *(const bf16x8*)((const char*)sB + boff + j * 1024);
#pragma unroll
        for (int i = 0; i < 4; ++i)
#pragma unroll
            for (int j = 0; j < 4; ++j)
                acc[i][j] = __builtin_amdgcn_mfma_f32_16x16x32_bf16(
                    af[i], bfr[j], acc[i][j], 0, 0, 0);
        __syncthreads();
    }

    const int rl = (lane >> 4) * 4, cl = lane & 15;

    if (MODE == 5) {
        // sA/sB are dead after the final barrier -- reuse as staging.
        float* stV = (float*)smem;               // [128][RCAP] = 7680 B
        int*   stI = (int*)(smem + 7680);        // [128][RCAP] = 7680 B
        int*   stC = (int*)(smem + 16384);       // [128]       =  512 B
        for (int r = t; r < 128; r += 256) stC[r] = 0;
        __syncthreads();
#pragma unroll
        for (int i = 0; i < 4; ++i) {
#pragma unroll
            for (int v = 0; v < 4; ++v) {
                int rloc = wm * 64 + i * 16 + rl + v;
                int gr = m0 + rloc;
                float q2b = q2v[gr];
                float th = thrv[gr];
#pragma unroll
                for (int j = 0; j < 4; ++j) {
                    int gc = n0 + wn * 64 + j * 16 + cl;
                    if (gc < nvalid) {
                        float d2 = d2_of(acc[i][j][v], q2b, c2v[gc]);
                        if (d2 <= th) {
                            int p = atomicAdd(&stC[rloc], 1);
                            if (p < RCAP) {
                                stV[rloc * RCAP + p] = d2;
                                stI[rloc * RCAP + p] = gc;
                            }
                        }
                    }
                }
            }
        }
        __syncthreads();
        for (int r = t; r < 128; r += 256) {
            int n = stC[r]; if (n > RCAP) n = RCAP;
            if (n > 0) {
                int gr = m0 + r;
                int gb = atomicAdd(&cnt[gr], n);
                for (int q = 0; q < n; ++q) {
                    int pos = gb + q;
                    if (pos < CAPC) {
                        candV[(size_t)gr * CAPC + pos] = stV[r * RCAP + q];
                        candI[(size_t)gr * CAPC + pos] = stI[r * RCAP + q];
                    }
                }
            }
        }
        return;
    }

#pragma unroll
    for (int i = 0; i < 4; ++i) {
#pragma unroll
        for (int j = 0; j < 4; ++j) {
            int gc = n0 + wn * 64 + j * 16 + cl;
#pragma unroll
            for (int v = 0; v < 4; ++v) {
                int gr = m0 + wm * 64 + i * 16 + rl + v;
                if (gr < M && gc < nvalid) {
                    float val = acc[i][j][v];
                    if (MODE == 2) {
                        ((float*)Cout)[(size_t)gr * ldc + gc] = val;
                    } else {
                        if (MODE == 1 || MODE == 3) val += bias[gc];
                        if (MODE == 1) val = fmaxf(val, 0.f);
                        ((ushort*)Cout)[(size_t)gr * ldc + gc] = f2bf(val);
                    }
                }
            }
        }
    }
}

// ---------------------------------------------------------------------------
// per-row radix-select of the 96th-SMALLEST d^2 over the first SAMP columns.
// ---------------------------------------------------------------------------
__global__ __launch_bounds__(256) void thr_select(const float* __restrict__ S,
                                                  int ld,
                                                  const float* __restrict__ q2v,
                                                  const float* __restrict__ c2v,
                                                  float* __restrict__ thrArr) {
    __shared__ unsigned keys[SAMP];
    __shared__ int hist[256];
    __shared__ int sel[2];
    const int b = blockIdx.x, t = threadIdx.x;
    const float q2b = q2v[b];
    for (int i = t; i < SAMP; i += 256)
        keys[i] = ~f2key(d2_of(S[(size_t)b * ld + i], q2b, c2v[i]));
    __syncthreads();
    unsigned prefix = 0, mask = 0;
    int rank = K_;
    for (int shift = 24; shift >= 0; shift -= 8) {
        hist[t & 255] = 0;
        __syncthreads();
        for (int i = t; i < SAMP; i += 256) {
            unsigned k = keys[i];
            if ((k & mask) == prefix) atomicAdd(&hist[(k >> shift) & 255], 1);
        }
        __syncthreads();
        if (t == 0) {
            int r = rank, d = 255;
            for (; d > 0; --d) { int c = hist[d]; if (r - c <= 0) break; r -= c; }
            sel[0] = d; sel[1] = (r < 1) ? 1 : r;
        }
        __syncthreads();
        prefix |= ((unsigned)sel[0]) << shift;
        rank = sel[1];
        mask |= (0xFFu << shift);
        __syncthreads();
    }
    if (t == 0) {
        unsigned key = ~prefix;
        thrArr[b] = __uint_as_float(key & 0x7FFFFFFFu);
    }
}

// ---------------------------------------------------------------------------
// per-row exact 96-smallest-d2 from candidate buffer via radix select
// (inverted keys) + compaction. topV receives d2.
// ---------------------------------------------------------------------------
__global__ __launch_bounds__(256) void final_select(const float* __restrict__ candV,
                                                    const int* __restrict__ candI,
                                                    const int* __restrict__ cnt,
                                                    float* __restrict__ topV,
                                                    int* __restrict__ topI) {
    __shared__ unsigned keys[CAPC];
    __shared__ int hist[256];
    __shared__ int sel[2];
    __shared__ int poscnt, eqcnt;
    const int b = blockIdx.x, t = threadIdx.x;
    int n = cnt[b]; if (n > CAPC) n = CAPC;
    for (int i = t; i < n; i += 256)
        keys[i] = ~f2key(candV[(size_t)b * CAPC + i]);
    __syncthreads();
    unsigned prefix = 0, mask = 0;
    int rank = K_;
    for (int shift = 24; shift >= 0; shift -= 8) {
        hist[t & 255] = 0;
        __syncthreads();
        for (int i = t; i < n; i += 256) {
            unsigned k = keys[i];
            if ((k & mask) == prefix) atomicAdd(&hist[(k >> shift) & 255], 1);
        }
        __syncthreads();
        if (t == 0) {
            int r = rank, d = 255;
            for (; d > 0; --d) { int c = hist[d]; if (r - c <= 0) break; r -= c; }
            sel[0] = d; sel[1] = (r < 1) ? 1 : r;
        }
        __syncthreads();
        prefix |= ((unsigned)sel[0]) << shift;
        rank = sel[1];
        mask |= (0xFFu << shift);
        __syncthreads();
    }
    unsigned kth = prefix;
    if (t == 0) { poscnt = 0; eqcnt = 0; }
    __syncthreads();
    for (int i = t; i < n; i += 256) {
        if (keys[i] > kth) {
            int p = atomicAdd(&poscnt, 1);
            topV[b * K_ + p] = candV[(size_t)b * CAPC + i];
            topI[b * K_ + p] = candI[(size_t)b * CAPC + i];
        }
    }
    __syncthreads();
    int base = poscnt;
    for (int i = t; i < n; i += 256) {
        if (keys[i] == kth) {
            int p = atomicAdd(&eqcnt, 1);
            if (base + p < K_) {
                topV[b * K_ + base + p] = candV[(size_t)b * CAPC + i];
                topI[b * K_ + base + p] = candI[(size_t)b * CAPC + i];
            }
        }
    }
}

__global__ void init_cnt(int* cnt) {
    int i = blockIdx.x * 256 + threadIdx.x;
    if (i < B_) cnt[i] = 0;
}

// ---------------------------------------------------------------------------
__global__ void conv_f2b(const float* __restrict__ in, ushort* __restrict__ out, int n) {
    int i = (blockIdx.x * 256 + threadIdx.x) * 4;
    int stride = gridDim.x * 256 * 4;
    for (; i < n; i += stride) {
        float4 v = *(const float4*)(in + i);
        ushort4 o;
        o.x = f2bf(v.x); o.y = f2bf(v.y); o.z = f2bf(v.z); o.w = f2bf(v.w);
        *(ushort4*)(out + i) = o;
    }
}

__global__ __launch_bounds__(256) void transpose_f2b(const float* __restrict__ in,
                                                     ushort* __restrict__ out,
                                                     int R, int Cn) {
    __shared__ float tile[32][33];
    int bx = blockIdx.x * 32, by = blockIdx.y * 32;
    int tx = threadIdx.x & 31, ty = threadIdx.x >> 5;
    int x = bx + tx;
#pragma unroll
    for (int dy = 0; dy < 32; dy += 8) {
        int y = by + ty + dy;
        if (x < Cn && y < R) tile[ty + dy][tx] = in[(size_t)y * Cn + x];
    }
    __syncthreads();
    int ox = by + tx;
#pragma unroll
    for (int dy = 0; dy < 32; dy += 8) {
        int oy = bx + ty + dy;
        if (ox < R && oy < Cn) out[(size_t)oy * R + ox] = f2bf(tile[tx][ty + dy]);
    }
}

__global__ __launch_bounds__(64) void rowsq_b(const ushort* __restrict__ X,
                                              float* __restrict__ outv) {
    const int r = blockIdx.x, t = threadIdx.x;
    const ushort* p = X + (size_t)r * H_;
    ushort4 a = *(const ushort4*)(p + t * 4);
    ushort4 b = *(const ushort4*)(p + 256 + t * 4);
    float ax = bf2f(a.x), ay = bf2f(a.y), az = bf2f(a.z), aw = bf2f(a.w);
    float bx = bf2f(b.x), by = bf2f(b.y), bz = bf2f(b.z), bw = bf2f(b.w);
    float v = ax * ax + ay * ay + az * az + aw * aw +
              bx * bx + by * by + bz * bz + bw * bw;
    for (int off = 32; off > 0; off >>= 1) v += __shfl_down(v, off);
    if (t == 0) outv[r] = v;
}

__global__ void bcomb_k(const float* __restrict__ b_enc,
                        const float* __restrict__ W_key,
                        const float* __restrict__ b_key,
                        float* __restrict__ b_comb) {
    int h = blockIdx.x * 256 + threadIdx.x;
    if (h >= H_) return;
    float acc = b_key[h];
    for (int m = 0; m < H_; ++m)
        acc = fmaf(b_enc[m], W_key[(size_t)m * H_ + h], acc);
    b_comb[h] = acc;
}

__global__ __launch_bounds__(128) void softmax_k(const float* __restrict__ topVal,
                                                 float* __restrict__ attn) {
    __shared__ float red[128];
    const int b = blockIdx.x, t = threadIdx.x;
    float v = (t < K_) ? -sqrtf(topVal[b * K_ + t]) : -FLT_MAX;
    red[t] = v; __syncthreads();
    for (int s = 64; s > 0; s >>= 1) {
        if (t < s) red[t] = fmaxf(red[t], red[t + s]);
        __syncthreads();
    }
    float m = red[0]; __syncthreads();
    float e = (t < K_) ? expf(v - m) : 0.f;
    red[t] = e; __syncthreads();
    for (int s = 64; s > 0; s >>= 1) {
        if (t < s) red[t] += red[t + s];
        __syncthreads();
    }
    float ssum = red[0];
    if (t < K_) attn[b * K_ + t] = e / ssum;
}

__global__ __launch_bounds__(128) void gather_diff_b(const float* __restrict__ XK,
                                                     const ushort* __restrict__ CK,
                                                     const int* __restrict__ topI,
                                                     ushort* __restrict__ diff,
                                                     int b0) {
    const int r = blockIdx.x;
    const int b = b0 + r / K_;
    const int idx = topI[b * K_ + (r % K_)];
    const int t = threadIdx.x;
    float4 xv = *(const float4*)(XK + (size_t)b * H_ + t * 4);
    ushort4 cv = *(const ushort4*)(CK + (size_t)idx * H_ + t * 4);
    ushort4 o;
    o.x = f2bf(xv.x - bf2f(cv.x));
    o.y = f2bf(xv.y - bf2f(cv.y));
    o.z = f2bf(xv.z - bf2f(cv.z));
    o.w = f2bf(xv.w - bf2f(cv.w));
    *(ushort4*)(diff + (size_t)r * H_ + t * 4) = o;
}

// attn-weighted reduction of h over k (BEFORE the W_t2 GEMM):
// hw[b,:] = sum_k attn[b,k] * h[(b-b0)*K+k, :]   (fp32 accum -> bf16)
__global__ __launch_bounds__(256) void wsum_h(const float* __restrict__ attn,
                                              const ushort* __restrict__ h,
                                              ushort* __restrict__ hw, int b0) {
    const int bl = blockIdx.x;
    const int b = b0 + bl;
    const int t = threadIdx.x;
    float a0 = 0.f, a1 = 0.f;
    const float* ap = attn + b * K_;
    for (int k = 0; k < K_; ++k) {
        float w = ap[k];
        const ushort* hr = h + (size_t)(bl * K_ + k) * H_;
        a0 = fmaf(w, bf2f(hr[t]), a0);
        a1 = fmaf(w, bf2f(hr[t + 256]), a1);
    }
    hw[(size_t)b * H_ + t]       = f2bf(a0);
    hw[(size_t)b * H_ + t + 256] = f2bf(a1);
}

// out = xe + sum_k attn*E[label[topI]] + tsum
__global__ __launch_bounds__(256) void final_out(const float* __restrict__ attn,
                                                 const int* __restrict__ topI,
                                                 const int* __restrict__ labels,
                                                 const float* __restrict__ E,
                                                 const float* __restrict__ tsum,
                                                 const float* __restrict__ xe,
                                                 float* __restrict__ out) {
    const int b = blockIdx.x, t = threadIdx.x;
    float a0 = 0.f, a1 = 0.f;
    for (int k = 0; k < K_; ++k) {
        float w = attn[b * K_ + k];
        int idx = topI[b * K_ + k];
        int lab = labels[idx];
        const float* el = E + (size_t)lab * H_;
        a0 = fmaf(w, el[t], a0);
        a1 = fmaf(w, el[t + 256], a1);
    }
    out[(size_t)b * H_ + t] =
        xe[(size_t)b * H_ + t] + a0 + tsum[(size_t)b * H_ + t];
    out[(size_t)b * H_ + t + 256] =
        xe[(size_t)b * H_ + t + 256] + a1 + tsum[(size_t)b * H_ + t + 256];
}

// ---------------------------------------------------------------------------
extern "C" void kernel_launch(void* const* d_in, const int* in_sizes, int n_in,
                              void* d_out, int out_size, void* d_ws, size_t ws_size,
                              hipStream_t stream) {
    const float* x      = (const float*)d_in[0];
    const float* cx     = (const float*)d_in[1];
    const int*   labels = (const int*)d_in[2];
    const float* W_enc  = (const float*)d_in[3];
    const float* b_enc  = (const float*)d_in[4];
    const float* W_key  = (const float*)d_in[5];
    const float* b_key  = (const float*)d_in[6];
    // d_in[7]=W_val, d_in[8]=b_val dead (gather unused in reference)
    const float* E_label = (const float*)d_in[9];
    const float* W_t1   = (const float*)d_in[10];
    const float* b_t1   = (const float*)d_in[11];
    const float* W_t2   = (const float*)d_in[12];
    float* out = (float*)d_out;

    char* base = (char*)d_ws;
    size_t off = 0;
    auto take = [&](size_t n) -> char* {
        char* p = base + off;
        off = (off + n + 255) & ~(size_t)255;
        return p;
    };
    float*  Wc    = (float*)take((size_t)D_ * H_ * 4);
    float*  bc    = (float*)take((size_t)H_ * 4);
    ushort* WcT   = (ushort*)take((size_t)H_ * D_ * 2);
    ushort* Wt1T  = (ushort*)take((size_t)H_ * H_ * 2);
    ushort* Wt2T  = (ushort*)take((size_t)H_ * H_ * 2);
    float*  xe    = (float*)take((size_t)B_ * H_ * 4);
    float*  xk    = (float*)take((size_t)B_ * H_ * 4);
    ushort* xkb   = (ushort*)take((size_t)B_ * H_ * 2);
    float*  q2    = (float*)take((size_t)B_ * 4);
    ushort* ckb   = (ushort*)take((size_t)N_ * H_ * 2);
    float*  c2    = (float*)take((size_t)N_ * 4);
    float*  topV  = (float*)take((size_t)B_ * K_ * 4);
    int*    topI  = (int*)take((size_t)B_ * K_ * 4);
    float*  thr   = (float*)take((size_t)B_ * 4);
    float*  attn  = (float*)take((size_t)B_ * K_ * 4);
    int*    cnt   = (int*)take((size_t)B_ * 4);
    float*  candV = (float*)take((size_t)B_ * CAPC * 4);
    int*    candI = (int*)take((size_t)B_ * CAPC * 4);
    ushort* hwAll = (ushort*)take((size_t)B_ * H_ * 2);
    float*  tsum  = (float*)take((size_t)B_ * H_ * 4);
    char*   big   = base + off;      // shared: cxb -> simSmall -> stage4 bufs
    size_t rem = (ws_size > off) ? (ws_size - off) : 0;

    ushort* cxb      = (ushort*)big;  // N*D*2 = 51.2 MB (dead after stage 2)
    float*  simSmall = (float*)big;   // B*SAMP*4 = 33.5 MB (dead after thr_select)

    long long bcq = (long long)(rem / ((size_t)K_ * H_ * 2 * 2));
    if (bcq > B_) bcq = B_;
    if (bcq < 1) bcq = 1;
    int Bc = (int)bcq;

    // stage 0: combined candidate weights + transposed bf16 weights
    {
        dim3 g(H_ / 64, D_ / 64);
        gemm_nn<0><<<g, 256, 0, stream>>>(W_enc, W_key, nullptr, Wc, D_, H_, H_);
        bcomb_k<<<(H_ + 255) / 256, 256, 0, stream>>>(b_enc, W_key, b_key, bc);
        dim3 gt1((H_ + 31) / 32, (D_ + 31) / 32);
        transpose_f2b<<<gt1, 256, 0, stream>>>(Wc, WcT, D_, H_);
        dim3 gt2((H_ + 31) / 32, (H_ + 31) / 32);
        transpose_f2b<<<gt2, 256, 0, stream>>>(W_t1, Wt1T, H_, H_);
        transpose_f2b<<<gt2, 256, 0, stream>>>(W_t2, Wt2T, H_, H_);
    }
    // stage 1: query encodes (fp32, tiny) + bf16 conversions
    {
        dim3 gx(H_ / 64, B_ / 64);
        gemm_nn<0><<<gx, 256, 0, stream>>>(x, W_enc, b_enc, xe, B_, H_, D_);
        gemm_nn<0><<<gx, 256, 0, stream>>>(x, Wc, bc, xk, B_, H_, D_);
        conv_f2b<<<1024, 256, 0, stream>>>(xk, xkb, B_ * H_);
        conv_f2b<<<2048, 256, 0, stream>>>(cx, cxb, N_ * D_);
    }
    // stage 2: candidate keys via bf16 MFMA (bias, no relu), SWZ=2
    {
        int mt = (N_ + 127) / 128;           // 782
        int mper = (mt + 7) / 8;             // 98
        gemm_nt<3, 2><<<8 * mper * 4, 256, 0, stream>>>(
            cxb, WcT, bc, nullptr, nullptr, nullptr, nullptr, nullptr, nullptr,
            ckb, N_, H_, D_, H_, H_, mper);
    }
    rowsq_b<<<N_, 64, 0, stream>>>(ckb, c2);
    rowsq_b<<<B_, 64, 0, stream>>>(xkb, q2);

    // stage 3a: sample sim GEMM (first SAMP cols, raw dot) -> d2 thresholds
    {
        int nper = (SAMP / 128 + 7) / 8;     // 8
        gemm_nt<2, 1><<<64 * nper, 256, 0, stream>>>(
            xkb, ckb, nullptr, nullptr, nullptr, nullptr, nullptr, nullptr,
            nullptr, simSmall, B_, N_, H_, SAMP, SAMP, nper);
        thr_select<<<B_, 256, 0, stream>>>(simSmall, SAMP, q2, c2, thr);
    }
    // stage 3b: fused sim GEMM + in-epilogue threshold filter over all N
    init_cnt<<<(B_ + 255) / 256, 256, 0, stream>>>(cnt);
    {
        int NT = (N_ + 127) / 128;           // 782
        int nper = (NT + 7) / 8;             // 98
        gemm_nt<5, 1><<<64 * nper, 256, 0, stream>>>(
            xkb, ckb, nullptr, q2, c2, thr, candV, candI, cnt,
            nullptr, B_, N_, H_, 0, N_, nper);
    }
    final_select<<<B_, 256, 0, stream>>>(candV, candI, cnt, topV, topI);
    softmax_k<<<B_, 128, 0, stream>>>(topV, attn);

    // stage 4: h = relu(diff@W1+b1); hw = sum_k attn*h (BEFORE W2);
    //          tsum = hw @ W2; out = xe + sum_k attn*E[label] + tsum
    ushort* diffB = (ushort*)big;
    ushort* hB = (ushort*)(big + (size_t)Bc * K_ * H_ * 2);
    for (int b0 = 0; b0 < B_; b0 += Bc) {
        int bcn = min(Bc, B_ - b0);
        int Mrows = bcn * K_;
        gather_diff_b<<<Mrows, 128, 0, stream>>>(xk, ckb, topI, diffB, b0);
        int mt4 = (Mrows + 127) / 128;
        int mper4 = (mt4 + 7) / 8;
        gemm_nt<1, 2><<<8 * mper4 * 4, 256, 0, stream>>>(
            diffB, Wt1T, b_t1, nullptr, nullptr, nullptr, nullptr, nullptr,
            nullptr, hB, Mrows, H_, H_, H_, H_, mper4);
        wsum_h<<<bcn, 256, 0, stream>>>(attn, hB, hwAll, b0);
    }
    {   // tiny GEMM: tsum[1024,512] = hwAll @ Wt2T^T (fp32 out via MODE 2)
        dim3 g(H_ / 128, B_ / 128);          // (4, 8)
        gemm_nt<2, 0><<<g, 256, 0, stream>>>(
            hwAll, Wt2T, nullptr, nullptr, nullptr, nullptr, nullptr, nullptr,
            nullptr, tsum, B_, H_, H_, H_, H_, 0);
    }
    final_out<<<B_, 256, 0, stream>>>(attn, topI, labels, E_label, tsum, xe, out);
}